// Round 11
// baseline (1047.375 us; speedup 1.0000x reference)
//
#include <hip/hip_runtime.h>
#include <hip/hip_fp16.h>

// ---------------- model dims ----------------
// B=128, W=128, N=64, HID=150, L=2
// gates = 4*HID = 600 ; enc input D = 3*N = 192 ; dec input = 2*HID = 300

typedef _Float16 v2h __attribute__((ext_vector_type(2)));
typedef _Float16 v8h __attribute__((ext_vector_type(8)));
typedef float v4f __attribute__((ext_vector_type(4)));

__device__ __forceinline__ float sigm(float x) {
    return 1.0f / (1.0f + __expf(-x));
}
__device__ __forceinline__ float tanhfast(float x) {
    return 2.0f / (1.0f + __expf(-2.0f * x)) - 1.0f;
}
__device__ __forceinline__ v2h pk2(float a, float b) {
    v2h r; r[0] = (_Float16)a; r[1] = (_Float16)b; return r;
}
__device__ __forceinline__ unsigned pku(float a, float b) {
    return __builtin_bit_cast(unsigned, pk2(a, b));
}
__device__ __forceinline__ v2h upk(unsigned u) { return __builtin_bit_cast(v2h, u); }
__device__ __forceinline__ float fdot2(v2h a, v2h b, float c) {
#if __has_builtin(__builtin_amdgcn_fdot2)
    return __builtin_amdgcn_fdot2(a, b, c, false);
#else
    return c + (float)a[0] * (float)b[0] + (float)a[1] * (float)b[1];
#endif
}

// LDS-only workgroup barrier (orders ds ops; leaves global loads in flight).
__device__ __forceinline__ void barrier_lds() {
    asm volatile("s_waitcnt lgkmcnt(0)" ::: "memory");
    __builtin_amdgcn_s_barrier();
}

// ---------------- copy x -> hs0 ----------------
__global__ void k_copy(const float* __restrict__ x, float* __restrict__ hs0) {
    int i = blockIdx.x * 256 + threadIdx.x;           // 262144 float4
    ((float4*)hs0)[i] = ((const float4*)x)[i];
}

// ---------------- conv branches (merged) ----------------
__global__ __launch_bounds__(256) void k_conv2(
    const float* __restrict__ x,
    const float* __restrict__ cw5, const float* __restrict__ cb5,
    const float* __restrict__ cw7, const float* __restrict__ cb7,
    float* __restrict__ hs1, float* __restrict__ hs2) {
    extern __shared__ float S[];
    float* xt = S;              // [70][68]
    float* wl = S + 70 * 68;    // [(t*16+i4)*256 + o*4 + j]
    int b = blockIdx.x, wh = blockIdx.y, br = blockIdx.z;
    int K = br ? 7 : 5;
    const float* cw = br ? cw7 : cw5;
    const float* cb = br ? cb7 : cb5;
    float* dst = br ? hs2 : hs1;
    int w0 = wh * 64;
    int tid = threadIdx.x;

    for (int f = tid; f < 70 * 64; f += 256) {
        int ww = f >> 6, i = f & 63;
        int wp = w0 - 3 + ww;
        xt[ww * 68 + i] = ((unsigned)wp < 128u) ? x[b * 8192 + wp * 64 + i] : 0.f;
    }
    int nw = K * 4096;
    for (int f = tid; f < nw; f += 256) {
        int j = f & 3, o = (f >> 2) & 63, i4 = (f >> 8) & 15, t = f >> 12;
        wl[f] = cw[(o * 64 + i4 * 4 + j) * K + t];
    }
    __syncthreads();

    int to = tid & 15, tw = tid >> 4;
    float acc[4][4] = {};
    int ob = 3 - (K >> 1);
    for (int t = 0; t < K; ++t) {
        int rbase = tw * 4 + t + ob;
        for (int i4 = 0; i4 < 16; ++i4) {
            float4 a0 = *(const float4*)&xt[(rbase + 0) * 68 + i4 * 4];
            float4 a1 = *(const float4*)&xt[(rbase + 1) * 68 + i4 * 4];
            float4 a2 = *(const float4*)&xt[(rbase + 2) * 68 + i4 * 4];
            float4 a3 = *(const float4*)&xt[(rbase + 3) * 68 + i4 * 4];
            const float* wrow = &wl[(t * 16 + i4) * 256];
            float4 b0 = *(const float4*)&wrow[to * 4];
            float4 b1 = *(const float4*)&wrow[(to + 16) * 4];
            float4 b2 = *(const float4*)&wrow[(to + 32) * 4];
            float4 b3 = *(const float4*)&wrow[(to + 48) * 4];
            #define DOT4(w_, a_) \
                acc[w_][0] = fmaf(a_.x, b0.x, acc[w_][0]); acc[w_][0] = fmaf(a_.y, b0.y, acc[w_][0]); \
                acc[w_][0] = fmaf(a_.z, b0.z, acc[w_][0]); acc[w_][0] = fmaf(a_.w, b0.w, acc[w_][0]); \
                acc[w_][1] = fmaf(a_.x, b1.x, acc[w_][1]); acc[w_][1] = fmaf(a_.y, b1.y, acc[w_][1]); \
                acc[w_][1] = fmaf(a_.z, b1.z, acc[w_][1]); acc[w_][1] = fmaf(a_.w, b1.w, acc[w_][1]); \
                acc[w_][2] = fmaf(a_.x, b2.x, acc[w_][2]); acc[w_][2] = fmaf(a_.y, b2.y, acc[w_][2]); \
                acc[w_][2] = fmaf(a_.z, b2.z, acc[w_][2]); acc[w_][2] = fmaf(a_.w, b2.w, acc[w_][2]); \
                acc[w_][3] = fmaf(a_.x, b3.x, acc[w_][3]); acc[w_][3] = fmaf(a_.y, b3.y, acc[w_][3]); \
                acc[w_][3] = fmaf(a_.z, b3.z, acc[w_][3]); acc[w_][3] = fmaf(a_.w, b3.w, acc[w_][3]);
            DOT4(0, a0)
            DOT4(1, a1)
            DOT4(2, a2)
            DOT4(3, a3)
            #undef DOT4
        }
    }
    #pragma unroll
    for (int wj = 0; wj < 4; ++wj) {
        int w = w0 + tw * 4 + wj;
        #pragma unroll
        for (int oj = 0; oj < 4; ++oj) {
            int o = to + 16 * oj;
            dst[b * 8192 + w * 64 + o] = fmaxf(acc[wj][oj] + cb[o], 0.f);
        }
    }
}

// ---------------- one STGAT layer (all 3 branches), fp16 dot2, in-place residual ----------------
// grid (128 b, 3 br), block 256, dyn LDS 77824 B -> 2 blocks/CU
__global__ __launch_bounds__(256, 2) void k_stgat(
    float* __restrict__ hs0, float* __restrict__ hs1, float* __restrict__ hs2,
    const float* __restrict__ gat_w, const float* __restrict__ gat_asrc,
    const float* __restrict__ gat_adst, const float* __restrict__ gat_b,
    const float* __restrict__ gcn_w, const float* __restrict__ gcn_b, int l) {
    extern __shared__ float S[];
    _Float16* Sh = (_Float16*)S;
    const int XHh = 0;           // xp fp16 [64 n][132 w]
    const int GHh = 8448;        // gw fp16 [128 wo][132 k]
    const int HHTh = 25344;      // h^T fp16 [128 wo][68 n]
    const int AHh = 34560;       // A fp16 [64 j][68 i]
    const int FHh = 8448;        // f^T fp16 [128 w][68 n]
    const int CHh = 0;           // cw fp16 [64 c][68 k]
    const int SDo = 17024;       // s[64], d[64]
    const int CSo = 17024;       // chunk sums [4][64]
    const int HGo = 8576;        // hg fp32 [128 w][66 c]

    int b = blockIdx.x, br = blockIdx.y, tid = threadIdx.x;
    float* hs = (br == 0 ? hs0 : (br == 1 ? hs1 : hs2)) + b * 8192;
    int wsel = br * 2 + l;
    const float* gw = gat_w + wsel * 16384;
    const float* asr = gat_asrc + wsel * 128;
    const float* ads = gat_adst + wsel * 128;
    const float* gb = gat_b + wsel * 128;
    const float* cwp = gcn_w + wsel * 4096;
    const float* cbp = gcn_b + wsel * 64;

    {
        const float4* hsv = (const float4*)hs;
        for (int mt = tid; mt < 512; mt += 256) {
            int ng = mt & 15, wg = mt >> 4;
            float4 r0 = hsv[(wg * 4 + 0) * 16 + ng];
            float4 r1 = hsv[(wg * 4 + 1) * 16 + ng];
            float4 r2 = hsv[(wg * 4 + 2) * 16 + ng];
            float4 r3 = hsv[(wg * 4 + 3) * 16 + ng];
            int n0 = ng * 4, ww = wg * 4;
            *(uint2*)&Sh[XHh + (n0 + 0) * 132 + ww] = make_uint2(pku(r0.x, r1.x), pku(r2.x, r3.x));
            *(uint2*)&Sh[XHh + (n0 + 1) * 132 + ww] = make_uint2(pku(r0.y, r1.y), pku(r2.y, r3.y));
            *(uint2*)&Sh[XHh + (n0 + 2) * 132 + ww] = make_uint2(pku(r0.z, r1.z), pku(r2.z, r3.z));
            *(uint2*)&Sh[XHh + (n0 + 3) * 132 + ww] = make_uint2(pku(r0.w, r1.w), pku(r2.w, r3.w));
        }
        const float4* gwv = (const float4*)gw;
        for (int f4 = tid; f4 < 4096; f4 += 256) {
            float4 v = gwv[f4];
            int wo = f4 >> 5, k4 = f4 & 31;
            *(uint2*)&Sh[GHh + wo * 132 + k4 * 4] = make_uint2(pku(v.x, v.y), pku(v.z, v.w));
        }
    }
    __syncthreads();

    int wq = tid & 15, nq = tid >> 4;
    {
        float asv[8], adv[8];
        #pragma unroll
        for (int c = 0; c < 8; ++c) { asv[c] = asr[wq + 16 * c]; adv[c] = ads[wq + 16 * c]; }
        float acc0[8] = {}, acc1[8] = {}, acc2[8] = {}, acc3[8] = {};
        const _Float16* Arow = Sh + XHh + nq * 4 * 132;
        const _Float16* Brow = Sh + GHh + wq * 132;
        for (int k4 = 0; k4 < 32; ++k4) {
            uint2 u0 = *(const uint2*)&Arow[k4 * 4];
            uint2 u1 = *(const uint2*)&Arow[132 + k4 * 4];
            uint2 u2 = *(const uint2*)&Arow[264 + k4 * 4];
            uint2 u3 = *(const uint2*)&Arow[396 + k4 * 4];
            v2h a0l = upk(u0.x), a0h = upk(u0.y), a1l = upk(u1.x), a1h = upk(u1.y);
            v2h a2l = upk(u2.x), a2h = upk(u2.y), a3l = upk(u3.x), a3h = upk(u3.y);
            #pragma unroll
            for (int c = 0; c < 8; ++c) {
                uint2 ub = *(const uint2*)&Brow[c * (16 * 132) + k4 * 4];
                v2h bl = upk(ub.x), bh = upk(ub.y);
                acc0[c] = fdot2(a0l, bl, acc0[c]); acc0[c] = fdot2(a0h, bh, acc0[c]);
                acc1[c] = fdot2(a1l, bl, acc1[c]); acc1[c] = fdot2(a1h, bh, acc1[c]);
                acc2[c] = fdot2(a2l, bl, acc2[c]); acc2[c] = fdot2(a2h, bh, acc2[c]);
                acc3[c] = fdot2(a3l, bl, acc3[c]); acc3[c] = fdot2(a3h, bh, acc3[c]);
            }
        }
        #pragma unroll
        for (int c = 0; c < 8; ++c)
            *(uint2*)&Sh[HHTh + (wq + 16 * c) * 68 + nq * 4] =
                make_uint2(pku(acc0[c], acc1[c]), pku(acc2[c], acc3[c]));
        float ps0 = 0, ps1 = 0, ps2 = 0, ps3 = 0, pd0 = 0, pd1 = 0, pd2 = 0, pd3 = 0;
        #pragma unroll
        for (int c = 0; c < 8; ++c) {
            ps0 = fmaf(acc0[c], asv[c], ps0); ps1 = fmaf(acc1[c], asv[c], ps1);
            ps2 = fmaf(acc2[c], asv[c], ps2); ps3 = fmaf(acc3[c], asv[c], ps3);
            pd0 = fmaf(acc0[c], adv[c], pd0); pd1 = fmaf(acc1[c], adv[c], pd1);
            pd2 = fmaf(acc2[c], adv[c], pd2); pd3 = fmaf(acc3[c], adv[c], pd3);
        }
        #pragma unroll
        for (int m = 1; m < 16; m <<= 1) {
            ps0 += __shfl_xor(ps0, m); ps1 += __shfl_xor(ps1, m);
            ps2 += __shfl_xor(ps2, m); ps3 += __shfl_xor(ps3, m);
            pd0 += __shfl_xor(pd0, m); pd1 += __shfl_xor(pd1, m);
            pd2 += __shfl_xor(pd2, m); pd3 += __shfl_xor(pd3, m);
        }
        if (wq == 0) {
            S[SDo + nq * 4 + 0] = ps0; S[SDo + nq * 4 + 1] = ps1;
            S[SDo + nq * 4 + 2] = ps2; S[SDo + nq * 4 + 3] = ps3;
            S[SDo + 64 + nq * 4 + 0] = pd0; S[SDo + 64 + nq * 4 + 1] = pd1;
            S[SDo + 64 + nq * 4 + 2] = pd2; S[SDo + 64 + nq * 4 + 3] = pd3;
        }
    }
    __syncthreads();

    {
        const float4* cwv = (const float4*)cwp;
        for (int f4 = tid; f4 < 1024; f4 += 256) {
            float4 v = cwv[f4];
            int c = f4 >> 4, k4 = f4 & 15;
            *(uint2*)&Sh[CHh + c * 68 + k4 * 4] = make_uint2(pku(v.x, v.y), pku(v.z, v.w));
        }
        if (tid < 64) {
            int j = tid;
            float dj = S[SDo + 64 + j];
            float mx = -1e30f;
            for (int i = 0; i < 64; ++i) {
                float e = S[SDo + i] + dj;
                e = (e > 0.f) ? e : 0.2f * e;
                mx = fmaxf(mx, e);
            }
            float sum = 0.f;
            for (int i = 0; i < 64; i += 2) {
                float e0 = S[SDo + i] + dj;     e0 = (e0 > 0.f) ? e0 : 0.2f * e0;
                float e1 = S[SDo + i + 1] + dj; e1 = (e1 > 0.f) ? e1 : 0.2f * e1;
                float x0 = __expf(e0 - mx), x1 = __expf(e1 - mx);
                sum += x0 + x1;
                *(unsigned*)&Sh[AHh + j * 68 + i] = pku(x0, x1);
            }
            float rinv = 1.f / sum;
            for (int i = 0; i < 64; i += 2) {
                v2h v = upk(*(const unsigned*)&Sh[AHh + j * 68 + i]);
                *(unsigned*)&Sh[AHh + j * 68 + i] = pku((float)v[0] * rinv, (float)v[1] * rinv);
            }
        }
    }
    __syncthreads();

    {
        float gbv[8];
        #pragma unroll
        for (int c = 0; c < 8; ++c) gbv[c] = gb[wq + 16 * c];
        float acc0[8] = {}, acc1[8] = {}, acc2[8] = {}, acc3[8] = {};
        const _Float16* Arow = Sh + AHh + nq * 4 * 68;
        const _Float16* Brow = Sh + HHTh + wq * 68;
        for (int k4 = 0; k4 < 16; ++k4) {
            uint2 u0 = *(const uint2*)&Arow[k4 * 4];
            uint2 u1 = *(const uint2*)&Arow[68 + k4 * 4];
            uint2 u2 = *(const uint2*)&Arow[136 + k4 * 4];
            uint2 u3 = *(const uint2*)&Arow[204 + k4 * 4];
            v2h a0l = upk(u0.x), a0h = upk(u0.y), a1l = upk(u1.x), a1h = upk(u1.y);
            v2h a2l = upk(u2.x), a2h = upk(u2.y), a3l = upk(u3.x), a3h = upk(u3.y);
            #pragma unroll
            for (int c = 0; c < 8; ++c) {
                uint2 ub = *(const uint2*)&Brow[c * (16 * 68) + k4 * 4];
                v2h bl = upk(ub.x), bh = upk(ub.y);
                acc0[c] = fdot2(a0l, bl, acc0[c]); acc0[c] = fdot2(a0h, bh, acc0[c]);
                acc1[c] = fdot2(a1l, bl, acc1[c]); acc1[c] = fdot2(a1h, bh, acc1[c]);
                acc2[c] = fdot2(a2l, bl, acc2[c]); acc2[c] = fdot2(a2h, bh, acc2[c]);
                acc3[c] = fdot2(a3l, bl, acc3[c]); acc3[c] = fdot2(a3h, bh, acc3[c]);
            }
        }
        #pragma unroll
        for (int c = 0; c < 8; ++c) {
            float f0 = fmaxf(acc0[c] + gbv[c], 0.f);
            float f1 = fmaxf(acc1[c] + gbv[c], 0.f);
            float f2 = fmaxf(acc2[c] + gbv[c], 0.f);
            float f3 = fmaxf(acc3[c] + gbv[c], 0.f);
            *(uint2*)&Sh[FHh + (wq + 16 * c) * 68 + nq * 4] = make_uint2(pku(f0, f1), pku(f2, f3));
        }
    }
    __syncthreads();

    {
        int cq = tid & 7, wg = tid >> 3;
        float acc0[8] = {}, acc1[8] = {}, acc2[8] = {}, acc3[8] = {};
        const _Float16* Arow = Sh + FHh + wg * 4 * 68;
        const _Float16* Brow = Sh + CHh + cq * 68;
        for (int k4 = 0; k4 < 16; ++k4) {
            uint2 u0 = *(const uint2*)&Arow[k4 * 4];
            uint2 u1 = *(const uint2*)&Arow[68 + k4 * 4];
            uint2 u2 = *(const uint2*)&Arow[136 + k4 * 4];
            uint2 u3 = *(const uint2*)&Arow[204 + k4 * 4];
            v2h a0l = upk(u0.x), a0h = upk(u0.y), a1l = upk(u1.x), a1h = upk(u1.y);
            v2h a2l = upk(u2.x), a2h = upk(u2.y), a3l = upk(u3.x), a3h = upk(u3.y);
            #pragma unroll
            for (int cc = 0; cc < 8; ++cc) {
                uint2 ub = *(const uint2*)&Brow[cc * (8 * 68) + k4 * 4];
                v2h bl = upk(ub.x), bh = upk(ub.y);
                acc0[cc] = fdot2(a0l, bl, acc0[cc]); acc0[cc] = fdot2(a0h, bh, acc0[cc]);
                acc1[cc] = fdot2(a1l, bl, acc1[cc]); acc1[cc] = fdot2(a1h, bh, acc1[cc]);
                acc2[cc] = fdot2(a2l, bl, acc2[cc]); acc2[cc] = fdot2(a2h, bh, acc2[cc]);
                acc3[cc] = fdot2(a3l, bl, acc3[cc]); acc3[cc] = fdot2(a3h, bh, acc3[cc]);
            }
        }
        #pragma unroll
        for (int cc = 0; cc < 8; ++cc) {
            int c = cq + 8 * cc;
            S[HGo + (wg * 4 + 0) * 66 + c] = acc0[cc];
            S[HGo + (wg * 4 + 1) * 66 + c] = acc1[cc];
            S[HGo + (wg * 4 + 2) * 66 + c] = acc2[cc];
            S[HGo + (wg * 4 + 3) * 66 + c] = acc3[cc];
        }
    }
    __syncthreads();

    {
        int c = tid & 63, q = tid >> 6;
        float local = 0.f;
        for (int i = 0; i < 32; ++i) {
            int w = q * 32 + i;
            local = fmaf(rsqrtf((float)(w + 1)), S[HGo + w * 66 + c], local);
        }
        S[CSo + q * 64 + c] = local;
    }
    __syncthreads();
    {
        int c = tid & 63, q = tid >> 6;
        float run = 0.f;
        for (int qq = 0; qq < q; ++qq) run += S[CSo + qq * 64 + c];
        float cbv = cbp[c];
        for (int i = 0; i < 32; ++i) {
            int w = q * 32 + i;
            float dv = rsqrtf((float)(w + 1));
            run = fmaf(dv, S[HGo + w * 66 + c], run);
            S[HGo + w * 66 + c] = fmaxf(fmaf(dv, run, cbv), 0.f);
        }
    }
    __syncthreads();

    {
        float4* hsv4 = (float4*)hs;
        for (int f4 = tid; f4 < 2048; f4 += 256) {
            int a = f4 >> 4, cc0 = (f4 & 15) * 4;
            float4 old = hsv4[f4];
            int n = a & 63, ahi = a >> 6;
            old.x += S[HGo + (cc0 * 2 + ahi) * 66 + n];
            old.y += S[HGo + ((cc0 + 1) * 2 + ahi) * 66 + n];
            old.z += S[HGo + ((cc0 + 2) * 2 + ahi) * 66 + n];
            old.w += S[HGo + ((cc0 + 3) * 2 + ahi) * 66 + n];
            hsv4[f4] = old;
        }
    }
}

// ---------------- encoder input GEMM (dir0 full), fp16 dot2, PERMUTED output ----------------
// Output gx0p[b][t][col] (col = unit-tile permutation, width 640):
//   g=(q,u): col = (u>>4)*64 + q*16 + (u&15)
__global__ __launch_bounds__(256) void k_encgemm2(
    const float* __restrict__ hs0, const float* __restrict__ hs1, const float* __restrict__ hs2,
    const float* __restrict__ wih, const float* __restrict__ bih, const float* __restrict__ bhh,
    float* __restrict__ gx0p) {
    __shared__ __align__(16) _Float16 Xh[128 * 72];
    __shared__ __align__(16) _Float16 Wh[128 * 72];
    int b = blockIdx.x, gy = blockIdx.y, tid = threadIdx.x;
    int g0 = gy * 128;
    int ty = tid >> 4, tx = tid & 15;
    float acc[8][8];
    #pragma unroll
    for (int i = 0; i < 8; ++i)
        #pragma unroll
        for (int j = 0; j < 8; ++j) acc[i][j] = 0.f;
    const float* hsb[3] = {hs0 + b * 8192, hs1 + b * 8192, hs2 + b * 8192};

    for (int c = 0; c < 3; ++c) {
        const float4* src = (const float4*)hsb[c];
        for (int f = tid; f < 2048; f += 256) {
            int t = f >> 4, k4 = f & 15;
            float4 v = src[f];
            int pos = (((k4 >> 1) ^ ((t >> 3) & 7)) << 1) + (k4 & 1);
            *(uint2*)&Xh[t * 72 + pos * 4] = make_uint2(pku(v.x, v.y), pku(v.z, v.w));
        }
        for (int f = tid; f < 2048; f += 256) {
            int g = f >> 4, k4 = f & 15;
            int gg = g0 + g;
            float4 v = (gg < 600) ? *(const float4*)&wih[gg * 192 + c * 64 + k4 * 4]
                                  : make_float4(0.f, 0.f, 0.f, 0.f);
            int pos = (((k4 >> 1) ^ ((g >> 3) & 7)) << 1) + (k4 & 1);
            *(uint2*)&Wh[g * 72 + pos * 4] = make_uint2(pku(v.x, v.y), pku(v.z, v.w));
        }
        __syncthreads();
        #pragma unroll
        for (int k8 = 0; k8 < 8; ++k8) {
            uint4 av[8];
            #pragma unroll
            for (int i = 0; i < 8; ++i) {
                int row = ty * 8 + i;
                av[i] = *(const uint4*)&Xh[row * 72 + (k8 ^ ((row >> 3) & 7)) * 8];
            }
            #pragma unroll
            for (int j = 0; j < 8; ++j) {
                int row = tx * 8 + j;
                uint4 bv = *(const uint4*)&Wh[row * 72 + (k8 ^ ((row >> 3) & 7)) * 8];
                v2h b0 = upk(bv.x), b1 = upk(bv.y), b2 = upk(bv.z), b3 = upk(bv.w);
                #pragma unroll
                for (int i = 0; i < 8; ++i) {
                    acc[i][j] = fdot2(upk(av[i].x), b0, acc[i][j]);
                    acc[i][j] = fdot2(upk(av[i].y), b1, acc[i][j]);
                    acc[i][j] = fdot2(upk(av[i].z), b2, acc[i][j]);
                    acc[i][j] = fdot2(upk(av[i].w), b3, acc[i][j]);
                }
            }
        }
        __syncthreads();
    }
    #pragma unroll
    for (int i = 0; i < 8; ++i) {
        int t = ty * 8 + i;
        float* orow = gx0p + (b * 128 + t) * 640;
        #pragma unroll
        for (int j = 0; j < 8; ++j) {
            int g = g0 + tx * 8 + j;
            if (g < 600) {
                int q = (g >= 450) ? 3 : (g >= 300) ? 2 : (g >= 150) ? 1 : 0;
                int u = g - q * 150;
                int col = ((u >> 4) << 6) + (q << 4) + (u & 15);
                orow[col] = acc[i][j] + bih[g] + bhh[g];
            }
        }
    }
}

// zero the pad columns of gx0p (cols with unit>=150: w==9, ul>=6)
__global__ void k_zpad(float* __restrict__ gx0p) {
    int f = blockIdx.x * 256 + threadIdx.x;     // 128*128*40
    if (f >= 655360) return;
    int pidx = f % 40, bt = f / 40;
    int ct = pidx / 10, ul = 6 + pidx % 10;
    gx0p[bt * 640 + 576 + ct * 16 + ul] = 0.f;
}

// ---------------- encoder dir1 gates at t=127 only ----------------
__global__ void k_encgx1(const float* __restrict__ hs0, const float* __restrict__ hs1,
                         const float* __restrict__ hs2, const float* __restrict__ wih,
                         const float* __restrict__ bih, const float* __restrict__ bhh,
                         float* __restrict__ gx1) {
    __shared__ __align__(16) float sh[192];
    int b = blockIdx.x, tid = threadIdx.x;
    if (tid < 192) {
        const float* src = (tid < 64 ? hs0 : (tid < 128 ? hs1 : hs2));
        sh[tid] = src[b * 8192 + 127 * 64 + (tid & 63)];
    }
    __syncthreads();
    const float* w1 = wih + 600 * 192;
    for (int g = tid; g < 600; g += 256) {
        float acc = bih[600 + g] + bhh[600 + g];
        const float4* wr = (const float4*)(w1 + g * 192);
        #pragma unroll 8
        for (int q = 0; q < 48; ++q) {
            float4 wv = wr[q];
            float4 hv = *(const float4*)&sh[q * 4];
            acc = fmaf(wv.x, hv.x, acc);
            acc = fmaf(wv.y, hv.y, acc);
            acc = fmaf(wv.z, hv.z, acc);
            acc = fmaf(wv.w, hv.w, acc);
        }
        gx1[b * 600 + g] = acc;
    }
}

// ---------------- prefix sums of dec_wih rows: PT[k][dg], k=0..300 ----------------
__global__ void k_ptpref(const float* __restrict__ dwih, float* __restrict__ PT) {
    int dg = blockIdx.x * 256 + threadIdx.x;
    if (dg >= 1200) return;
    const float* wr = dwih + dg * 300;
    float run = 0.f;
    PT[dg] = 0.f;
    for (int k = 0; k < 300; ++k) {
        run += wr[k];
        PT[(k + 1) * 1200 + dg] = run;
    }
}

// ---------------- PD[(dirt*600+g)*4 + seg] ----------------
__global__ void k_pd(const float* __restrict__ PT, float* __restrict__ PD) {
    int id = blockIdx.x * 256 + threadIdx.x;
    if (id >= 153600) return;                 // 2*128*600
    int g = id % 600;
    int tt = id / 600;
    int t = tt & 127, dir = tt >> 7;
    int dg = dir * 600 + g;
    int base = t * 300;
    int j0 = base >> 7;
    int ke1 = (j0 + 1) * 128 - base;
    int ke2 = ke1 + 128; ke2 = ke2 > 300 ? 300 : ke2;
    int ke3 = ke1 + 256; ke3 = ke3 > 300 ? 300 : ke3;
    float p1 = PT[ke1 * 1200 + dg];
    float p2 = PT[ke2 * 1200 + dg];
    float p3 = PT[ke3 * 1200 + dg];
    float p4 = PT[300 * 1200 + dg];
    float4 o = {p1, p2 - p1, p3 - p2, p4 - p3};
    *(float4*)&PD[id * 4] = o;
}

// ---------------- pack Whh into MFMA B-frag order ----------------
// Bfrag flat idx = (((w*5+kt)*4+ct)*64 + lane)*8 + j ; value:
//   q=ct, u=16w+(lane&15), k=kt*32+8*(lane>>4)+j ; Whh[q*150+u][k], 0-padded.
__global__ void k_prepB(const float* __restrict__ whh, _Float16* __restrict__ Bp, int ndir) {
    int f = blockIdx.x * 256 + threadIdx.x;
    int per = 102400;
    if (f >= per * ndir) return;
    int dir = f / per, r = f % per;
    int j = r & 7, rest = r >> 3;
    int lane = rest & 63; rest >>= 6;
    int ct = rest & 3; rest >>= 2;
    int kt = rest % 5, w = rest / 5;
    int u = 16 * w + (lane & 15);
    int k = kt * 32 + 8 * (lane >> 4) + j;
    float v = (u < 150 && k < 150) ? whh[dir * 90000 + (ct * 150 + u) * 150 + k] : 0.f;
    Bp[f] = (_Float16)v;
}

// ---------------- expand decoder x-part: gxd[dirt][b][t][col] fp16 ----------------
// grid 256 (dirt = dir*128 + t), block 256
__global__ __launch_bounds__(256) void k_gxd(
    const float* __restrict__ PD, const float* __restrict__ hend,
    const float* __restrict__ dbih, const float* __restrict__ dbhh,
    _Float16* __restrict__ gxd) {
    __shared__ float PDs[2400 + 600];
    int dt = blockIdx.x, tid = threadIdx.x;
    int dir = dt >> 7, t = dt & 127;
    for (int g = tid; g < 600; g += 256) {
        float4 p = *(const float4*)&PD[((dir * 128 + t) * 600 + g) * 4];
        *(float4*)&PDs[g * 4] = p;
        PDs[2400 + g] = dbih[dir * 600 + g] + dbhh[dir * 600 + g];
    }
    __syncthreads();
    int j0 = (t * 300) >> 7;
    for (int b = 0; b < 128; ++b) {
        float e0 = hend[b * 300 + j0];
        float e1 = (j0 + 1 < 300) ? hend[b * 300 + j0 + 1] : 0.f;
        float e2 = (j0 + 2 < 300) ? hend[b * 300 + j0 + 2] : 0.f;
        float e3 = (j0 + 3 < 300) ? hend[b * 300 + j0 + 3] : 0.f;
        _Float16* orow = gxd + (((dir * 128 + b) * 128) + t) * 640;
        for (int col = tid; col < 640; col += 256) {
            int u = 16 * (col >> 6) + (col & 15);
            int q = (col >> 4) & 3;
            float v = 0.f;
            if (u < 150) {
                int g = q * 150 + u;
                const float* p = &PDs[g * 4];
                v = PDs[2400 + g] + e0 * p[0] + e1 * p[1] + e2 * p[2] + e3 * p[3];
            }
            orow[col] = (_Float16)v;
        }
    }
}

// ---------------- MFMA-batched encoder LSTM ----------------
// bid<8: scan block for 16 batches (b0=bid*16); bid>=8: single bwd step (b=bid-8).
// 640 threads = 10 waves; wave w owns gate-cols [64w,64w+64) in gate-major tiles:
//   ct 0..3 = gates i,f,g,o of units 16w..16w+15. Lane holds all 4 gates of
//   (unit = 16w+(lane&15), batches rows 4*(lane>>4)+reg) -> zero shuffles.
__global__ __launch_bounds__(640) void k_enclstm_m(
    const float* __restrict__ gx0p, const float* __restrict__ gx1,
    const _Float16* __restrict__ BpE, float* __restrict__ h_end) {
    int bid = blockIdx.x, tid = threadIdx.x;
    if (bid >= 8) {   // bwd single step
        int b = bid - 8, t = tid;
        if (t < 150) {
            float ai = gx1[b * 600 + t];
            float ag = gx1[b * 600 + 300 + t];
            float ao = gx1[b * 600 + 450 + t];
            float c = sigm(ai) * tanhfast(ag);
            h_end[b * 300 + 150 + t] = sigm(ao) * tanhfast(c);
        }
        return;
    }
    __shared__ __align__(16) _Float16 hA[2][5][512];
    int b0 = bid * 16;
    int w = tid >> 6, l = tid & 63;
    // load B-frags (80 VGPRs)
    v8h Bf[5][4];
    #pragma unroll
    for (int kt = 0; kt < 5; ++kt)
        #pragma unroll
        for (int ct = 0; ct < 4; ++ct)
            Bf[kt][ct] = *(const v8h*)(BpE + (((w * 5 + kt) * 4 + ct) * 64 + l) * 8);
    for (int i = tid; i < 5120; i += 640) ((_Float16*)hA)[i] = (_Float16)0.f;
    float cst[4] = {0.f, 0.f, 0.f, 0.f};
    int row0 = 4 * (l >> 4);
    int u = 16 * w + (l & 15);
    int kloc = u & 31, tile = u >> 5;
    int wl2 = ((row0 & 15)) | ((kloc >> 3) << 4);   // lane-slot base (reg adds to row)
    const float* gpb = gx0p + ((long)(b0 + row0) * 128) * 640 + w * 64 + (l & 15);
    barrier_lds();
    for (int s = 0; s < 128; ++s) {
        // x-part as C-in
        v4f acc[4];
        #pragma unroll
        for (int ct = 0; ct < 4; ++ct) {
            #pragma unroll
            for (int reg = 0; reg < 4; ++reg)
                acc[ct][reg] = gpb[(long)reg * 81920 + (long)s * 640 + ct * 16];
        }
        #pragma unroll
        for (int kt = 0; kt < 5; ++kt) {
            v8h Af = *(const v8h*)&hA[s & 1][kt][l * 8];
            acc[0] = __builtin_amdgcn_mfma_f32_16x16x32_f16(Af, Bf[kt][0], acc[0], 0, 0, 0);
            acc[1] = __builtin_amdgcn_mfma_f32_16x16x32_f16(Af, Bf[kt][1], acc[1], 0, 0, 0);
            acc[2] = __builtin_amdgcn_mfma_f32_16x16x32_f16(Af, Bf[kt][2], acc[2], 0, 0, 0);
            acc[3] = __builtin_amdgcn_mfma_f32_16x16x32_f16(Af, Bf[kt][3], acc[3], 0, 0, 0);
        }
        _Float16* hw = &hA[(s + 1) & 1][tile][0];
        #pragma unroll
        for (int reg = 0; reg < 4; ++reg) {
            float iv = sigm(acc[0][reg]);
            float fv = sigm(acc[1][reg]);
            float gv = tanhfast(acc[2][reg]);
            float ov = sigm(acc[3][reg]);
            cst[reg] = fmaf(fv, cst[reg], iv * gv);
            float h = ov * tanhfast(cst[reg]);
            hw[(wl2 + reg) * 8 + (kloc & 7)] = (_Float16)h;
            if (s == 127 && u < 150) h_end[(b0 + row0 + reg) * 300 + u] = h;
        }
        barrier_lds();
    }
}

// ---------------- MFMA-batched decoder LSTM ----------------
// grid 16: dir = bid>>3, b0 = (bid&7)*16. x from gxd fp16; writes decH fp16.
__global__ __launch_bounds__(640) void k_declstm_m(
    const _Float16* __restrict__ gxd, const _Float16* __restrict__ BpD,
    _Float16* __restrict__ decH) {
    __shared__ __align__(16) _Float16 hA[2][5][512];
    int bid = blockIdx.x, tid = threadIdx.x;
    int dir = bid >> 3, b0 = (bid & 7) * 16;
    int w = tid >> 6, l = tid & 63;
    v8h Bf[5][4];
    #pragma unroll
    for (int kt = 0; kt < 5; ++kt)
        #pragma unroll
        for (int ct = 0; ct < 4; ++ct)
            Bf[kt][ct] = *(const v8h*)(BpD + (long)dir * 102400 +
                                       (((w * 5 + kt) * 4 + ct) * 64 + l) * 8);
    for (int i = tid; i < 5120; i += 640) ((_Float16*)hA)[i] = (_Float16)0.f;
    float cst[4] = {0.f, 0.f, 0.f, 0.f};
    int row0 = 4 * (l >> 4);
    int u = 16 * w + (l & 15);
    int kloc = u & 31, tile = u >> 5;
    int wl2 = (row0 & 15) | ((kloc >> 3) << 4);
    const _Float16* gpb = gxd + ((long)((dir * 128 + b0 + row0)) * 128) * 640 + w * 64 + (l & 15);
    barrier_lds();
    for (int s = 0; s < 128; ++s) {
        int t = dir ? (127 - s) : s;
        v4f acc[4];
        #pragma unroll
        for (int ct = 0; ct < 4; ++ct) {
            #pragma unroll
            for (int reg = 0; reg < 4; ++reg)
                acc[ct][reg] = (float)gpb[(long)reg * 81920 + (long)t * 640 + ct * 16];
        }
        #pragma unroll
        for (int kt = 0; kt < 5; ++kt) {
            v8h Af = *(const v8h*)&hA[s & 1][kt][l * 8];
            acc[0] = __builtin_amdgcn_mfma_f32_16x16x32_f16(Af, Bf[kt][0], acc[0], 0, 0, 0);
            acc[1] = __builtin_amdgcn_mfma_f32_16x16x32_f16(Af, Bf[kt][1], acc[1], 0, 0, 0);
            acc[2] = __builtin_amdgcn_mfma_f32_16x16x32_f16(Af, Bf[kt][2], acc[2], 0, 0, 0);
            acc[3] = __builtin_amdgcn_mfma_f32_16x16x32_f16(Af, Bf[kt][3], acc[3], 0, 0, 0);
        }
        _Float16* hw = &hA[(s + 1) & 1][tile][0];
        #pragma unroll
        for (int reg = 0; reg < 4; ++reg) {
            float iv = sigm(acc[0][reg]);
            float fv = sigm(acc[1][reg]);
            float gv = tanhfast(acc[2][reg]);
            float ov = sigm(acc[3][reg]);
            cst[reg] = fmaf(fv, cst[reg], iv * gv);
            float h = ov * tanhfast(cst[reg]);
            hw[(wl2 + reg) * 8 + (kloc & 7)] = (_Float16)h;
            if (u < 150)
                decH[((b0 + row0 + reg) * 128 + t) * 300 + dir * 150 + u] = (_Float16)h;
        }
        barrier_lds();
    }
}

// ---------------- final: out = dec(fp16) @ fc_w^T + fc_b, fp16 dot2 ----------------
__global__ __launch_bounds__(256) void k_fingemm(const _Float16* __restrict__ decH,
                                                 const float* __restrict__ fw,
                                                 const float* __restrict__ fb,
                                                 float* __restrict__ out) {
    __shared__ __align__(16) unsigned AsT[16 * 68];
    __shared__ __align__(16) unsigned FwT[16 * 68];
    int r0 = blockIdx.x * 64, tid = threadIdx.x;
    int ty = tid >> 4, tx = tid & 15;
    float acc[4][4];
    #pragma unroll
    for (int r = 0; r < 4; ++r)
        #pragma unroll
        for (int c = 0; c < 4; ++c) acc[r][c] = 0.f;
    for (int kc = 0; kc < 10; ++kc) {
        int k0 = kc * 32;
        for (int f = tid; f < 1024; f += 256) {
            int m = f >> 4, kk2 = f & 15;
            int k = k0 + kk2 * 2;
            AsT[kk2 * 68 + m] =
                (k + 1 < 300) ? *(const unsigned*)&decH[(r0 + m) * 300 + k] : 0u;
        }
        for (int f = tid; f < 1024; f += 256) {
            int n = f >> 4, kk2 = f & 15;
            int k = k0 + kk2 * 2;
            FwT[kk2 * 68 + n] =
                (k + 1 < 300) ? pku(fw[n * 300 + k], fw[n * 300 + k + 1]) : 0u;
        }
        __syncthreads();
        #pragma unroll 4
        for (int kk2 = 0; kk2 < 16; ++kk2) {
            uint4 a4 = *(const uint4*)&AsT[kk2 * 68 + ty * 4];
            uint4 w4 = *(const uint4*)&FwT[kk2 * 68 + tx * 4];
            v2h a0 = upk(a4.x), a1 = upk(a4.y), a2 = upk(a4.z), a3 = upk(a4.w);
            v2h w0 = upk(w4.x), w1 = upk(w4.y), w2 = upk(w4.z), w3 = upk(w4.w);
            acc[0][0] = fdot2(a0, w0, acc[0][0]); acc[0][1] = fdot2(a0, w1, acc[0][1]);
            acc[0][2] = fdot2(a0, w2, acc[0][2]); acc[0][3] = fdot2(a0, w3, acc[0][3]);
            acc[1][0] = fdot2(a1, w0, acc[1][0]); acc[1][1] = fdot2(a1, w1, acc[1][1]);
            acc[1][2] = fdot2(a1, w2, acc[1][2]); acc[1][3] = fdot2(a1, w3, acc[1][3]);
            acc[2][0] = fdot2(a2, w0, acc[2][0]); acc[2][1] = fdot2(a2, w1, acc[2][1]);
            acc[2][2] = fdot2(a2, w2, acc[2][2]); acc[2][3] = fdot2(a2, w3, acc[2][3]);
            acc[3][0] = fdot2(a3, w0, acc[3][0]); acc[3][1] = fdot2(a3, w1, acc[3][1]);
            acc[3][2] = fdot2(a3, w2, acc[3][2]); acc[3][3] = fdot2(a3, w3, acc[3][3]);
        }
        __syncthreads();
    }
    for (int r = 0; r < 4; ++r) {
        int m = r0 + ty * 4 + r;
        float4 o4;
        o4.x = acc[r][0] + fb[tx * 4 + 0];
        o4.y = acc[r][1] + fb[tx * 4 + 1];
        o4.z = acc[r][2] + fb[tx * 4 + 2];
        o4.w = acc[r][3] + fb[tx * 4 + 3];
        *(float4*)&out[m * 64 + tx * 4] = o4;
    }
}

// ---------------- host launcher ----------------
extern "C" void kernel_launch(void* const* d_in, const int* in_sizes, int n_in,
                              void* d_out, int out_size, void* d_ws, size_t ws_size,
                              hipStream_t stream) {
    const float* x = (const float*)d_in[0];
    const float* c2w = (const float*)d_in[3];
    const float* c2b = (const float*)d_in[4];
    const float* c3w = (const float*)d_in[5];
    const float* c3b = (const float*)d_in[6];
    const float* gatw = (const float*)d_in[7];
    const float* gatas = (const float*)d_in[8];
    const float* gatad = (const float*)d_in[9];
    const float* gatb = (const float*)d_in[10];
    const float* gcnw = (const float*)d_in[11];
    const float* gcnb = (const float*)d_in[12];
    const float* lwih = (const float*)d_in[13];
    const float* lwhh = (const float*)d_in[14];
    const float* lbih = (const float*)d_in[15];
    const float* lbhh = (const float*)d_in[16];
    const float* dwih = (const float*)d_in[17];
    const float* dwhh = (const float*)d_in[18];
    const float* dbih = (const float*)d_in[19];
    const float* dbhh = (const float*)d_in[20];
    const float* fcw = (const float*)d_in[21];
    const float* fcb = (const float*)d_in[22];
    float* out = (float*)d_out;
    float* ws = (float*)d_ws;

    float* hs0 = ws;                          // 1,048,576
    float* hs1 = ws + 1048576;                // 1,048,576
    float* hs2 = ws + 2097152;                // 1,048,576
    float* gx0p = ws + 3145728;               // 10,485,760 (128*128*640)
    float* gx1 = ws + 13631488;               // 76,800
    float* hend = ws + 13708288;              // 38,400
    float* PT = ws + 13746688;                // 361,200
    _Float16* decH = (_Float16*)(ws + 14107888);   // 4,915,200 halfs (2,457,600 f)
    _Float16* BpE = (_Float16*)(ws + 16565488);    // 102,400 halfs (51,200 f)
    _Float16* BpD = (_Float16*)(ws + 16616688);    // 204,800 halfs (102,400 f)
    float* PD = hs0;                          // overlays hs0 (dead after encgemm/encgx1)
    _Float16* gxd = (_Float16*)gx0p;          // overlays gx0p (dead after enc LSTM)

    k_prepB<<<400, 256, 0, stream>>>(lwhh, BpE, 1);
    k_prepB<<<800, 256, 0, stream>>>(dwhh, BpD, 2);
    k_copy<<<1024, 256, 0, stream>>>(x, hs0);
    k_conv2<<<dim3(128, 2, 2), 256, (70 * 68 + 7 * 16 * 256) * 4, stream>>>(
        x, c2w, c2b, c3w, c3b, hs1, hs2);
    for (int l = 0; l < 2; ++l)
        k_stgat<<<dim3(128, 3), 256, 77824, stream>>>(hs0, hs1, hs2, gatw, gatas,
                                                      gatad, gatb, gcnw, gcnb, l);
    k_encgemm2<<<dim3(128, 5), 256, 0, stream>>>(hs0, hs1, hs2, lwih, lbih, lbhh, gx0p);
    k_zpad<<<2560, 256, 0, stream>>>(gx0p);
    k_encgx1<<<128, 256, 0, stream>>>(hs0, hs1, hs2, lwih, lbih, lbhh, gx1);
    k_ptpref<<<5, 256, 0, stream>>>(dwih, PT);
    k_pd<<<600, 256, 0, stream>>>(PT, PD);   // hs0 region now dead
    k_enclstm_m<<<136, 640, 0, stream>>>(gx0p, gx1, BpE, hend);
    k_gxd<<<256, 256, 0, stream>>>(PD, hend, dbih, dbhh, gxd);   // gx0p region now dead
    k_declstm_m<<<16, 640, 0, stream>>>(gxd, BpD, decH);
    k_fingemm<<<256, 256, 0, stream>>>(decH, fcw, fcb, out);
}

// Round 12
// 1017.163 us; speedup vs baseline: 1.0297x; 1.0297x over previous
//
#include <hip/hip_runtime.h>
#include <hip/hip_fp16.h>

// ---------------- model dims ----------------
// B=128, W=128, N=64, HID=150, L=2
// gates = 4*HID = 600 ; enc input D = 3*N = 192 ; dec input = 2*HID = 300

typedef _Float16 v2h __attribute__((ext_vector_type(2)));
typedef _Float16 v8h __attribute__((ext_vector_type(8)));
typedef float v4f __attribute__((ext_vector_type(4)));

__device__ __forceinline__ float sigm(float x) {
    return 1.0f / (1.0f + __expf(-x));
}
__device__ __forceinline__ float tanhfast(float x) {
    return 2.0f / (1.0f + __expf(-2.0f * x)) - 1.0f;
}
__device__ __forceinline__ v2h pk2(float a, float b) {
    v2h r; r[0] = (_Float16)a; r[1] = (_Float16)b; return r;
}
__device__ __forceinline__ unsigned pku(float a, float b) {
    return __builtin_bit_cast(unsigned, pk2(a, b));
}
__device__ __forceinline__ v2h upk(unsigned u) { return __builtin_bit_cast(v2h, u); }
__device__ __forceinline__ float fdot2(v2h a, v2h b, float c) {
#if __has_builtin(__builtin_amdgcn_fdot2)
    return __builtin_amdgcn_fdot2(a, b, c, false);
#else
    return c + (float)a[0] * (float)b[0] + (float)a[1] * (float)b[1];
#endif
}

// LDS-only workgroup barrier (orders ds ops; leaves global loads in flight).
__device__ __forceinline__ void barrier_lds() {
    asm volatile("s_waitcnt lgkmcnt(0)" ::: "memory");
    __builtin_amdgcn_s_barrier();
}

// ---- MFMA LSTM step machinery (2-buffer B ring; see kernel comments) ----
// Expects in scope: hA[2][5][512], l, tile, kloc, wl2, row0, u, BpW,
// xv0..3, xn0..3 (v4f), cst[4], Ba[4], Bb[4].
#define MSTAGE(ktU, BU, BP, ktP)                                            \
    BP[0] = *(const v8h*)(BpW + (ktP) * 2048 + 0);                          \
    BP[1] = *(const v8h*)(BpW + (ktP) * 2048 + 512);                        \
    BP[2] = *(const v8h*)(BpW + (ktP) * 2048 + 1024);                       \
    BP[3] = *(const v8h*)(BpW + (ktP) * 2048 + 1536);                       \
    {                                                                       \
        v8h Af_ = *(const v8h*)&hA[BI_][ktU][l * 8];                        \
        a0 = __builtin_amdgcn_mfma_f32_16x16x32_f16(Af_, BU[0], a0, 0, 0, 0); \
        a1 = __builtin_amdgcn_mfma_f32_16x16x32_f16(Af_, BU[1], a1, 0, 0, 0); \
        a2 = __builtin_amdgcn_mfma_f32_16x16x32_f16(Af_, BU[2], a2, 0, 0, 0); \
        a3 = __builtin_amdgcn_mfma_f32_16x16x32_f16(Af_, BU[3], a3, 0, 0, 0); \
    }

#define MSTEP(B0_, B1_, BI__, S_, XPRE_, HSTORE_)                           \
    {                                                                       \
        v4f a0 = xv0, a1 = xv1, a2 = xv2, a3 = xv3;                         \
        XPRE_                                                               \
        {                                                                   \
            const int BI_ = (BI__);                                         \
            MSTAGE(0, B0_, B1_, 1)                                          \
            MSTAGE(1, B1_, B0_, 2)                                          \
            MSTAGE(2, B0_, B1_, 3)                                          \
            MSTAGE(3, B1_, B0_, 4)                                          \
            MSTAGE(4, B0_, B1_, 0)                                          \
        }                                                                   \
        _Float16* hw_ = &hA[(BI__) ^ 1][tile][0];                           \
        _Pragma("unroll")                                                   \
        for (int reg = 0; reg < 4; ++reg) {                                 \
            float iv = sigm(a0[reg]);                                       \
            float fv = sigm(a1[reg]);                                       \
            float gv = tanhfast(a2[reg]);                                   \
            float ov = sigm(a3[reg]);                                       \
            cst[reg] = fmaf(fv, cst[reg], iv * gv);                         \
            float h = ov * tanhfast(cst[reg]);                              \
            hw_[(wl2 + reg) * 8 + (kloc & 7)] = (_Float16)h;                \
            HSTORE_                                                         \
        }                                                                   \
        xv0 = xn0; xv1 = xn1; xv2 = xn2; xv3 = xn3;                         \
        barrier_lds();                                                      \
    }

// ---------------- copy x -> hs0 ----------------
__global__ void k_copy(const float* __restrict__ x, float* __restrict__ hs0) {
    int i = blockIdx.x * 256 + threadIdx.x;           // 262144 float4
    ((float4*)hs0)[i] = ((const float4*)x)[i];
}

// ---------------- conv branches (merged) ----------------
__global__ __launch_bounds__(256) void k_conv2(
    const float* __restrict__ x,
    const float* __restrict__ cw5, const float* __restrict__ cb5,
    const float* __restrict__ cw7, const float* __restrict__ cb7,
    float* __restrict__ hs1, float* __restrict__ hs2) {
    extern __shared__ float S[];
    float* xt = S;              // [70][68]
    float* wl = S + 70 * 68;    // [(t*16+i4)*256 + o*4 + j]
    int b = blockIdx.x, wh = blockIdx.y, br = blockIdx.z;
    int K = br ? 7 : 5;
    const float* cw = br ? cw7 : cw5;
    const float* cb = br ? cb7 : cb5;
    float* dst = br ? hs2 : hs1;
    int w0 = wh * 64;
    int tid = threadIdx.x;

    for (int f = tid; f < 70 * 64; f += 256) {
        int ww = f >> 6, i = f & 63;
        int wp = w0 - 3 + ww;
        xt[ww * 68 + i] = ((unsigned)wp < 128u) ? x[b * 8192 + wp * 64 + i] : 0.f;
    }
    int nw = K * 4096;
    for (int f = tid; f < nw; f += 256) {
        int j = f & 3, o = (f >> 2) & 63, i4 = (f >> 8) & 15, t = f >> 12;
        wl[f] = cw[(o * 64 + i4 * 4 + j) * K + t];
    }
    __syncthreads();

    int to = tid & 15, tw = tid >> 4;
    float acc[4][4] = {};
    int ob = 3 - (K >> 1);
    for (int t = 0; t < K; ++t) {
        int rbase = tw * 4 + t + ob;
        for (int i4 = 0; i4 < 16; ++i4) {
            float4 a0 = *(const float4*)&xt[(rbase + 0) * 68 + i4 * 4];
            float4 a1 = *(const float4*)&xt[(rbase + 1) * 68 + i4 * 4];
            float4 a2 = *(const float4*)&xt[(rbase + 2) * 68 + i4 * 4];
            float4 a3 = *(const float4*)&xt[(rbase + 3) * 68 + i4 * 4];
            const float* wrow = &wl[(t * 16 + i4) * 256];
            float4 b0 = *(const float4*)&wrow[to * 4];
            float4 b1 = *(const float4*)&wrow[(to + 16) * 4];
            float4 b2 = *(const float4*)&wrow[(to + 32) * 4];
            float4 b3 = *(const float4*)&wrow[(to + 48) * 4];
            #define DOT4(w_, a_) \
                acc[w_][0] = fmaf(a_.x, b0.x, acc[w_][0]); acc[w_][0] = fmaf(a_.y, b0.y, acc[w_][0]); \
                acc[w_][0] = fmaf(a_.z, b0.z, acc[w_][0]); acc[w_][0] = fmaf(a_.w, b0.w, acc[w_][0]); \
                acc[w_][1] = fmaf(a_.x, b1.x, acc[w_][1]); acc[w_][1] = fmaf(a_.y, b1.y, acc[w_][1]); \
                acc[w_][1] = fmaf(a_.z, b1.z, acc[w_][1]); acc[w_][1] = fmaf(a_.w, b1.w, acc[w_][1]); \
                acc[w_][2] = fmaf(a_.x, b2.x, acc[w_][2]); acc[w_][2] = fmaf(a_.y, b2.y, acc[w_][2]); \
                acc[w_][2] = fmaf(a_.z, b2.z, acc[w_][2]); acc[w_][2] = fmaf(a_.w, b2.w, acc[w_][2]); \
                acc[w_][3] = fmaf(a_.x, b3.x, acc[w_][3]); acc[w_][3] = fmaf(a_.y, b3.y, acc[w_][3]); \
                acc[w_][3] = fmaf(a_.z, b3.z, acc[w_][3]); acc[w_][3] = fmaf(a_.w, b3.w, acc[w_][3]);
            DOT4(0, a0)
            DOT4(1, a1)
            DOT4(2, a2)
            DOT4(3, a3)
            #undef DOT4
        }
    }
    #pragma unroll
    for (int wj = 0; wj < 4; ++wj) {
        int w = w0 + tw * 4 + wj;
        #pragma unroll
        for (int oj = 0; oj < 4; ++oj) {
            int o = to + 16 * oj;
            dst[b * 8192 + w * 64 + o] = fmaxf(acc[wj][oj] + cb[o], 0.f);
        }
    }
}

// ---------------- one STGAT layer (all 3 branches), fp16 dot2, in-place residual ----------------
// grid (128 b, 3 br), block 256, dyn LDS 77824 B -> 2 blocks/CU
__global__ __launch_bounds__(256, 2) void k_stgat(
    float* __restrict__ hs0, float* __restrict__ hs1, float* __restrict__ hs2,
    const float* __restrict__ gat_w, const float* __restrict__ gat_asrc,
    const float* __restrict__ gat_adst, const float* __restrict__ gat_b,
    const float* __restrict__ gcn_w, const float* __restrict__ gcn_b, int l) {
    extern __shared__ float S[];
    _Float16* Sh = (_Float16*)S;
    const int XHh = 0;           // xp fp16 [64 n][132 w]
    const int GHh = 8448;        // gw fp16 [128 wo][132 k]
    const int HHTh = 25344;      // h^T fp16 [128 wo][68 n]
    const int AHh = 34560;       // A fp16 [64 j][68 i]
    const int FHh = 8448;        // f^T fp16 [128 w][68 n]
    const int CHh = 0;           // cw fp16 [64 c][68 k]
    const int SDo = 17024;       // s[64], d[64]
    const int CSo = 17024;       // chunk sums [4][64]
    const int HGo = 8576;        // hg fp32 [128 w][66 c]

    int b = blockIdx.x, br = blockIdx.y, tid = threadIdx.x;
    float* hs = (br == 0 ? hs0 : (br == 1 ? hs1 : hs2)) + b * 8192;
    int wsel = br * 2 + l;
    const float* gw = gat_w + wsel * 16384;
    const float* asr = gat_asrc + wsel * 128;
    const float* ads = gat_adst + wsel * 128;
    const float* gb = gat_b + wsel * 128;
    const float* cwp = gcn_w + wsel * 4096;
    const float* cbp = gcn_b + wsel * 64;

    {
        const float4* hsv = (const float4*)hs;
        for (int mt = tid; mt < 512; mt += 256) {
            int ng = mt & 15, wg = mt >> 4;
            float4 r0 = hsv[(wg * 4 + 0) * 16 + ng];
            float4 r1 = hsv[(wg * 4 + 1) * 16 + ng];
            float4 r2 = hsv[(wg * 4 + 2) * 16 + ng];
            float4 r3 = hsv[(wg * 4 + 3) * 16 + ng];
            int n0 = ng * 4, ww = wg * 4;
            *(uint2*)&Sh[XHh + (n0 + 0) * 132 + ww] = make_uint2(pku(r0.x, r1.x), pku(r2.x, r3.x));
            *(uint2*)&Sh[XHh + (n0 + 1) * 132 + ww] = make_uint2(pku(r0.y, r1.y), pku(r2.y, r3.y));
            *(uint2*)&Sh[XHh + (n0 + 2) * 132 + ww] = make_uint2(pku(r0.z, r1.z), pku(r2.z, r3.z));
            *(uint2*)&Sh[XHh + (n0 + 3) * 132 + ww] = make_uint2(pku(r0.w, r1.w), pku(r2.w, r3.w));
        }
        const float4* gwv = (const float4*)gw;
        for (int f4 = tid; f4 < 4096; f4 += 256) {
            float4 v = gwv[f4];
            int wo = f4 >> 5, k4 = f4 & 31;
            *(uint2*)&Sh[GHh + wo * 132 + k4 * 4] = make_uint2(pku(v.x, v.y), pku(v.z, v.w));
        }
    }
    __syncthreads();

    int wq = tid & 15, nq = tid >> 4;
    {
        float asv[8], adv[8];
        #pragma unroll
        for (int c = 0; c < 8; ++c) { asv[c] = asr[wq + 16 * c]; adv[c] = ads[wq + 16 * c]; }
        float acc0[8] = {}, acc1[8] = {}, acc2[8] = {}, acc3[8] = {};
        const _Float16* Arow = Sh + XHh + nq * 4 * 132;
        const _Float16* Brow = Sh + GHh + wq * 132;
        for (int k4 = 0; k4 < 32; ++k4) {
            uint2 u0 = *(const uint2*)&Arow[k4 * 4];
            uint2 u1 = *(const uint2*)&Arow[132 + k4 * 4];
            uint2 u2 = *(const uint2*)&Arow[264 + k4 * 4];
            uint2 u3 = *(const uint2*)&Arow[396 + k4 * 4];
            v2h a0l = upk(u0.x), a0h = upk(u0.y), a1l = upk(u1.x), a1h = upk(u1.y);
            v2h a2l = upk(u2.x), a2h = upk(u2.y), a3l = upk(u3.x), a3h = upk(u3.y);
            #pragma unroll
            for (int c = 0; c < 8; ++c) {
                uint2 ub = *(const uint2*)&Brow[c * (16 * 132) + k4 * 4];
                v2h bl = upk(ub.x), bh = upk(ub.y);
                acc0[c] = fdot2(a0l, bl, acc0[c]); acc0[c] = fdot2(a0h, bh, acc0[c]);
                acc1[c] = fdot2(a1l, bl, acc1[c]); acc1[c] = fdot2(a1h, bh, acc1[c]);
                acc2[c] = fdot2(a2l, bl, acc2[c]); acc2[c] = fdot2(a2h, bh, acc2[c]);
                acc3[c] = fdot2(a3l, bl, acc3[c]); acc3[c] = fdot2(a3h, bh, acc3[c]);
            }
        }
        #pragma unroll
        for (int c = 0; c < 8; ++c)
            *(uint2*)&Sh[HHTh + (wq + 16 * c) * 68 + nq * 4] =
                make_uint2(pku(acc0[c], acc1[c]), pku(acc2[c], acc3[c]));
        float ps0 = 0, ps1 = 0, ps2 = 0, ps3 = 0, pd0 = 0, pd1 = 0, pd2 = 0, pd3 = 0;
        #pragma unroll
        for (int c = 0; c < 8; ++c) {
            ps0 = fmaf(acc0[c], asv[c], ps0); ps1 = fmaf(acc1[c], asv[c], ps1);
            ps2 = fmaf(acc2[c], asv[c], ps2); ps3 = fmaf(acc3[c], asv[c], ps3);
            pd0 = fmaf(acc0[c], adv[c], pd0); pd1 = fmaf(acc1[c], adv[c], pd1);
            pd2 = fmaf(acc2[c], adv[c], pd2); pd3 = fmaf(acc3[c], adv[c], pd3);
        }
        #pragma unroll
        for (int m = 1; m < 16; m <<= 1) {
            ps0 += __shfl_xor(ps0, m); ps1 += __shfl_xor(ps1, m);
            ps2 += __shfl_xor(ps2, m); ps3 += __shfl_xor(ps3, m);
            pd0 += __shfl_xor(pd0, m); pd1 += __shfl_xor(pd1, m);
            pd2 += __shfl_xor(pd2, m); pd3 += __shfl_xor(pd3, m);
        }
        if (wq == 0) {
            S[SDo + nq * 4 + 0] = ps0; S[SDo + nq * 4 + 1] = ps1;
            S[SDo + nq * 4 + 2] = ps2; S[SDo + nq * 4 + 3] = ps3;
            S[SDo + 64 + nq * 4 + 0] = pd0; S[SDo + 64 + nq * 4 + 1] = pd1;
            S[SDo + 64 + nq * 4 + 2] = pd2; S[SDo + 64 + nq * 4 + 3] = pd3;
        }
    }
    __syncthreads();

    {
        const float4* cwv = (const float4*)cwp;
        for (int f4 = tid; f4 < 1024; f4 += 256) {
            float4 v = cwv[f4];
            int c = f4 >> 4, k4 = f4 & 15;
            *(uint2*)&Sh[CHh + c * 68 + k4 * 4] = make_uint2(pku(v.x, v.y), pku(v.z, v.w));
        }
        if (tid < 64) {
            int j = tid;
            float dj = S[SDo + 64 + j];
            float mx = -1e30f;
            for (int i = 0; i < 64; ++i) {
                float e = S[SDo + i] + dj;
                e = (e > 0.f) ? e : 0.2f * e;
                mx = fmaxf(mx, e);
            }
            float sum = 0.f;
            for (int i = 0; i < 64; i += 2) {
                float e0 = S[SDo + i] + dj;     e0 = (e0 > 0.f) ? e0 : 0.2f * e0;
                float e1 = S[SDo + i + 1] + dj; e1 = (e1 > 0.f) ? e1 : 0.2f * e1;
                float x0 = __expf(e0 - mx), x1 = __expf(e1 - mx);
                sum += x0 + x1;
                *(unsigned*)&Sh[AHh + j * 68 + i] = pku(x0, x1);
            }
            float rinv = 1.f / sum;
            for (int i = 0; i < 64; i += 2) {
                v2h v = upk(*(const unsigned*)&Sh[AHh + j * 68 + i]);
                *(unsigned*)&Sh[AHh + j * 68 + i] = pku((float)v[0] * rinv, (float)v[1] * rinv);
            }
        }
    }
    __syncthreads();

    {
        float gbv[8];
        #pragma unroll
        for (int c = 0; c < 8; ++c) gbv[c] = gb[wq + 16 * c];
        float acc0[8] = {}, acc1[8] = {}, acc2[8] = {}, acc3[8] = {};
        const _Float16* Arow = Sh + AHh + nq * 4 * 68;
        const _Float16* Brow = Sh + HHTh + wq * 68;
        for (int k4 = 0; k4 < 16; ++k4) {
            uint2 u0 = *(const uint2*)&Arow[k4 * 4];
            uint2 u1 = *(const uint2*)&Arow[68 + k4 * 4];
            uint2 u2 = *(const uint2*)&Arow[136 + k4 * 4];
            uint2 u3 = *(const uint2*)&Arow[204 + k4 * 4];
            v2h a0l = upk(u0.x), a0h = upk(u0.y), a1l = upk(u1.x), a1h = upk(u1.y);
            v2h a2l = upk(u2.x), a2h = upk(u2.y), a3l = upk(u3.x), a3h = upk(u3.y);
            #pragma unroll
            for (int c = 0; c < 8; ++c) {
                uint2 ub = *(const uint2*)&Brow[c * (16 * 68) + k4 * 4];
                v2h bl = upk(ub.x), bh = upk(ub.y);
                acc0[c] = fdot2(a0l, bl, acc0[c]); acc0[c] = fdot2(a0h, bh, acc0[c]);
                acc1[c] = fdot2(a1l, bl, acc1[c]); acc1[c] = fdot2(a1h, bh, acc1[c]);
                acc2[c] = fdot2(a2l, bl, acc2[c]); acc2[c] = fdot2(a2h, bh, acc2[c]);
                acc3[c] = fdot2(a3l, bl, acc3[c]); acc3[c] = fdot2(a3h, bh, acc3[c]);
            }
        }
        #pragma unroll
        for (int c = 0; c < 8; ++c) {
            float f0 = fmaxf(acc0[c] + gbv[c], 0.f);
            float f1 = fmaxf(acc1[c] + gbv[c], 0.f);
            float f2 = fmaxf(acc2[c] + gbv[c], 0.f);
            float f3 = fmaxf(acc3[c] + gbv[c], 0.f);
            *(uint2*)&Sh[FHh + (wq + 16 * c) * 68 + nq * 4] = make_uint2(pku(f0, f1), pku(f2, f3));
        }
    }
    __syncthreads();

    {
        int cq = tid & 7, wg = tid >> 3;
        float acc0[8] = {}, acc1[8] = {}, acc2[8] = {}, acc3[8] = {};
        const _Float16* Arow = Sh + FHh + wg * 4 * 68;
        const _Float16* Brow = Sh + CHh + cq * 68;
        for (int k4 = 0; k4 < 16; ++k4) {
            uint2 u0 = *(const uint2*)&Arow[k4 * 4];
            uint2 u1 = *(const uint2*)&Arow[68 + k4 * 4];
            uint2 u2 = *(const uint2*)&Arow[136 + k4 * 4];
            uint2 u3 = *(const uint2*)&Arow[204 + k4 * 4];
            v2h a0l = upk(u0.x), a0h = upk(u0.y), a1l = upk(u1.x), a1h = upk(u1.y);
            v2h a2l = upk(u2.x), a2h = upk(u2.y), a3l = upk(u3.x), a3h = upk(u3.y);
            #pragma unroll
            for (int cc = 0; cc < 8; ++cc) {
                uint2 ub = *(const uint2*)&Brow[cc * (8 * 68) + k4 * 4];
                v2h bl = upk(ub.x), bh = upk(ub.y);
                acc0[cc] = fdot2(a0l, bl, acc0[cc]); acc0[cc] = fdot2(a0h, bh, acc0[cc]);
                acc1[cc] = fdot2(a1l, bl, acc1[cc]); acc1[cc] = fdot2(a1h, bh, acc1[cc]);
                acc2[cc] = fdot2(a2l, bl, acc2[cc]); acc2[cc] = fdot2(a2h, bh, acc2[cc]);
                acc3[cc] = fdot2(a3l, bl, acc3[cc]); acc3[cc] = fdot2(a3h, bh, acc3[cc]);
            }
        }
        #pragma unroll
        for (int cc = 0; cc < 8; ++cc) {
            int c = cq + 8 * cc;
            S[HGo + (wg * 4 + 0) * 66 + c] = acc0[cc];
            S[HGo + (wg * 4 + 1) * 66 + c] = acc1[cc];
            S[HGo + (wg * 4 + 2) * 66 + c] = acc2[cc];
            S[HGo + (wg * 4 + 3) * 66 + c] = acc3[cc];
        }
    }
    __syncthreads();

    {
        int c = tid & 63, q = tid >> 6;
        float local = 0.f;
        for (int i = 0; i < 32; ++i) {
            int w = q * 32 + i;
            local = fmaf(rsqrtf((float)(w + 1)), S[HGo + w * 66 + c], local);
        }
        S[CSo + q * 64 + c] = local;
    }
    __syncthreads();
    {
        int c = tid & 63, q = tid >> 6;
        float run = 0.f;
        for (int qq = 0; qq < q; ++qq) run += S[CSo + qq * 64 + c];
        float cbv = cbp[c];
        for (int i = 0; i < 32; ++i) {
            int w = q * 32 + i;
            float dv = rsqrtf((float)(w + 1));
            run = fmaf(dv, S[HGo + w * 66 + c], run);
            S[HGo + w * 66 + c] = fmaxf(fmaf(dv, run, cbv), 0.f);
        }
    }
    __syncthreads();

    {
        float4* hsv4 = (float4*)hs;
        for (int f4 = tid; f4 < 2048; f4 += 256) {
            int a = f4 >> 4, cc0 = (f4 & 15) * 4;
            float4 old = hsv4[f4];
            int n = a & 63, ahi = a >> 6;
            old.x += S[HGo + (cc0 * 2 + ahi) * 66 + n];
            old.y += S[HGo + ((cc0 + 1) * 2 + ahi) * 66 + n];
            old.z += S[HGo + ((cc0 + 2) * 2 + ahi) * 66 + n];
            old.w += S[HGo + ((cc0 + 3) * 2 + ahi) * 66 + n];
            hsv4[f4] = old;
        }
    }
}

// ---------------- encoder input GEMM (dir0 full), fp16 dot2, PERMUTED output ----------------
// Output gx0p[b][t][col] (col = unit-tile permutation, width 640):
//   g=(q,u): col = (u>>4)*64 + q*16 + (u&15)
__global__ __launch_bounds__(256) void k_encgemm2(
    const float* __restrict__ hs0, const float* __restrict__ hs1, const float* __restrict__ hs2,
    const float* __restrict__ wih, const float* __restrict__ bih, const float* __restrict__ bhh,
    float* __restrict__ gx0p) {
    __shared__ __align__(16) _Float16 Xh[128 * 72];
    __shared__ __align__(16) _Float16 Wh[128 * 72];
    int b = blockIdx.x, gy = blockIdx.y, tid = threadIdx.x;
    int g0 = gy * 128;
    int ty = tid >> 4, tx = tid & 15;
    float acc[8][8];
    #pragma unroll
    for (int i = 0; i < 8; ++i)
        #pragma unroll
        for (int j = 0; j < 8; ++j) acc[i][j] = 0.f;
    const float* hsb[3] = {hs0 + b * 8192, hs1 + b * 8192, hs2 + b * 8192};

    for (int c = 0; c < 3; ++c) {
        const float4* src = (const float4*)hsb[c];
        for (int f = tid; f < 2048; f += 256) {
            int t = f >> 4, k4 = f & 15;
            float4 v = src[f];
            int pos = (((k4 >> 1) ^ ((t >> 3) & 7)) << 1) + (k4 & 1);
            *(uint2*)&Xh[t * 72 + pos * 4] = make_uint2(pku(v.x, v.y), pku(v.z, v.w));
        }
        for (int f = tid; f < 2048; f += 256) {
            int g = f >> 4, k4 = f & 15;
            int gg = g0 + g;
            float4 v = (gg < 600) ? *(const float4*)&wih[gg * 192 + c * 64 + k4 * 4]
                                  : make_float4(0.f, 0.f, 0.f, 0.f);
            int pos = (((k4 >> 1) ^ ((g >> 3) & 7)) << 1) + (k4 & 1);
            *(uint2*)&Wh[g * 72 + pos * 4] = make_uint2(pku(v.x, v.y), pku(v.z, v.w));
        }
        __syncthreads();
        #pragma unroll
        for (int k8 = 0; k8 < 8; ++k8) {
            uint4 av[8];
            #pragma unroll
            for (int i = 0; i < 8; ++i) {
                int row = ty * 8 + i;
                av[i] = *(const uint4*)&Xh[row * 72 + (k8 ^ ((row >> 3) & 7)) * 8];
            }
            #pragma unroll
            for (int j = 0; j < 8; ++j) {
                int row = tx * 8 + j;
                uint4 bv = *(const uint4*)&Wh[row * 72 + (k8 ^ ((row >> 3) & 7)) * 8];
                v2h b0 = upk(bv.x), b1 = upk(bv.y), b2 = upk(bv.z), b3 = upk(bv.w);
                #pragma unroll
                for (int i = 0; i < 8; ++i) {
                    acc[i][j] = fdot2(upk(av[i].x), b0, acc[i][j]);
                    acc[i][j] = fdot2(upk(av[i].y), b1, acc[i][j]);
                    acc[i][j] = fdot2(upk(av[i].z), b2, acc[i][j]);
                    acc[i][j] = fdot2(upk(av[i].w), b3, acc[i][j]);
                }
            }
        }
        __syncthreads();
    }
    #pragma unroll
    for (int i = 0; i < 8; ++i) {
        int t = ty * 8 + i;
        float* orow = gx0p + (b * 128 + t) * 640;
        #pragma unroll
        for (int j = 0; j < 8; ++j) {
            int g = g0 + tx * 8 + j;
            if (g < 600) {
                int q = (g >= 450) ? 3 : (g >= 300) ? 2 : (g >= 150) ? 1 : 0;
                int u = g - q * 150;
                int col = ((u >> 4) << 6) + (q << 4) + (u & 15);
                orow[col] = acc[i][j] + bih[g] + bhh[g];
            }
        }
    }
}

// zero the pad columns of gx0p (cols with unit>=150: w==9, ul>=6)
__global__ void k_zpad(float* __restrict__ gx0p) {
    int f = blockIdx.x * 256 + threadIdx.x;     // 128*128*40
    if (f >= 655360) return;
    int pidx = f % 40, bt = f / 40;
    int ct = pidx / 10, ul = 6 + pidx % 10;
    gx0p[bt * 640 + 576 + ct * 16 + ul] = 0.f;
}

// ---------------- encoder dir1 gates at t=127 only ----------------
__global__ void k_encgx1(const float* __restrict__ hs0, const float* __restrict__ hs1,
                         const float* __restrict__ hs2, const float* __restrict__ wih,
                         const float* __restrict__ bih, const float* __restrict__ bhh,
                         float* __restrict__ gx1) {
    __shared__ __align__(16) float sh[192];
    int b = blockIdx.x, tid = threadIdx.x;
    if (tid < 192) {
        const float* src = (tid < 64 ? hs0 : (tid < 128 ? hs1 : hs2));
        sh[tid] = src[b * 8192 + 127 * 64 + (tid & 63)];
    }
    __syncthreads();
    const float* w1 = wih + 600 * 192;
    for (int g = tid; g < 600; g += 256) {
        float acc = bih[600 + g] + bhh[600 + g];
        const float4* wr = (const float4*)(w1 + g * 192);
        #pragma unroll 8
        for (int q = 0; q < 48; ++q) {
            float4 wv = wr[q];
            float4 hv = *(const float4*)&sh[q * 4];
            acc = fmaf(wv.x, hv.x, acc);
            acc = fmaf(wv.y, hv.y, acc);
            acc = fmaf(wv.z, hv.z, acc);
            acc = fmaf(wv.w, hv.w, acc);
        }
        gx1[b * 600 + g] = acc;
    }
}

// ---------------- prefix sums of dec_wih rows: PT[k][dg], k=0..300 ----------------
__global__ void k_ptpref(const float* __restrict__ dwih, float* __restrict__ PT) {
    int dg = blockIdx.x * 256 + threadIdx.x;
    if (dg >= 1200) return;
    const float* wr = dwih + dg * 300;
    float run = 0.f;
    PT[dg] = 0.f;
    for (int k = 0; k < 300; ++k) {
        run += wr[k];
        PT[(k + 1) * 1200 + dg] = run;
    }
}

// ---------------- PD[(dirt*600+g)*4 + seg] ----------------
__global__ void k_pd(const float* __restrict__ PT, float* __restrict__ PD) {
    int id = blockIdx.x * 256 + threadIdx.x;
    if (id >= 153600) return;                 // 2*128*600
    int g = id % 600;
    int tt = id / 600;
    int t = tt & 127, dir = tt >> 7;
    int dg = dir * 600 + g;
    int base = t * 300;
    int j0 = base >> 7;
    int ke1 = (j0 + 1) * 128 - base;
    int ke2 = ke1 + 128; ke2 = ke2 > 300 ? 300 : ke2;
    int ke3 = ke1 + 256; ke3 = ke3 > 300 ? 300 : ke3;
    float p1 = PT[ke1 * 1200 + dg];
    float p2 = PT[ke2 * 1200 + dg];
    float p3 = PT[ke3 * 1200 + dg];
    float p4 = PT[300 * 1200 + dg];
    float4 o = {p1, p2 - p1, p3 - p2, p4 - p3};
    *(float4*)&PD[id * 4] = o;
}

// ---------------- pack Whh into MFMA B-frag order ----------------
// Bfrag flat idx = (((w*5+kt)*4+ct)*64 + lane)*8 + j ; value:
//   q=ct, u=16w+(lane&15), k=kt*32+8*(lane>>4)+j ; Whh[q*150+u][k], 0-padded.
__global__ void k_prepB(const float* __restrict__ whh, _Float16* __restrict__ Bp, int ndir) {
    int f = blockIdx.x * 256 + threadIdx.x;
    int per = 102400;
    if (f >= per * ndir) return;
    int dir = f / per, r = f % per;
    int j = r & 7, rest = r >> 3;
    int lane = rest & 63; rest >>= 6;
    int ct = rest & 3; rest >>= 2;
    int kt = rest % 5, w = rest / 5;
    int u = 16 * w + (lane & 15);
    int k = kt * 32 + 8 * (lane >> 4) + j;
    float v = (u < 150 && k < 150) ? whh[dir * 90000 + (ct * 150 + u) * 150 + k] : 0.f;
    Bp[f] = (_Float16)v;
}

// ---------------- expand decoder x-part: gxd[dirt][b][t][col] fp16 ----------------
// grid 256 (dirt = dir*128 + t), block 256
__global__ __launch_bounds__(256) void k_gxd(
    const float* __restrict__ PD, const float* __restrict__ hend,
    const float* __restrict__ dbih, const float* __restrict__ dbhh,
    _Float16* __restrict__ gxd) {
    __shared__ float PDs[2400 + 600];
    int dt = blockIdx.x, tid = threadIdx.x;
    int dir = dt >> 7, t = dt & 127;
    for (int g = tid; g < 600; g += 256) {
        float4 p = *(const float4*)&PD[((dir * 128 + t) * 600 + g) * 4];
        *(float4*)&PDs[g * 4] = p;
        PDs[2400 + g] = dbih[dir * 600 + g] + dbhh[dir * 600 + g];
    }
    __syncthreads();
    int j0 = (t * 300) >> 7;
    for (int b = 0; b < 128; ++b) {
        float e0 = hend[b * 300 + j0];
        float e1 = (j0 + 1 < 300) ? hend[b * 300 + j0 + 1] : 0.f;
        float e2 = (j0 + 2 < 300) ? hend[b * 300 + j0 + 2] : 0.f;
        float e3 = (j0 + 3 < 300) ? hend[b * 300 + j0 + 3] : 0.f;
        _Float16* orow = gxd + (((dir * 128 + b) * 128) + t) * 640;
        for (int col = tid; col < 640; col += 256) {
            int u = 16 * (col >> 6) + (col & 15);
            int q = (col >> 4) & 3;
            float v = 0.f;
            if (u < 150) {
                int g = q * 150 + u;
                const float* p = &PDs[g * 4];
                v = PDs[2400 + g] + e0 * p[0] + e1 * p[1] + e2 * p[2] + e3 * p[3];
            }
            orow[col] = (_Float16)v;
        }
    }
}

// ---------------- MFMA-batched encoder LSTM (v2: x-prefetch + 2-buffer B ring) ----------------
// bid<8: scan block for 16 batches (b0=bid*16); bid>=8: single bwd step (b=bid-8).
__global__ __launch_bounds__(640) void k_enclstm_m(
    const float* __restrict__ gx0p, const float* __restrict__ gx1,
    const _Float16* __restrict__ BpE, float* __restrict__ h_end) {
    int bid = blockIdx.x, tid = threadIdx.x;
    if (bid >= 8) {   // bwd single step
        int b = bid - 8, t = tid;
        if (t < 150) {
            float ai = gx1[b * 600 + t];
            float ag = gx1[b * 600 + 300 + t];
            float ao = gx1[b * 600 + 450 + t];
            float c = sigm(ai) * tanhfast(ag);
            h_end[b * 300 + 150 + t] = sigm(ao) * tanhfast(c);
        }
        return;
    }
    __shared__ __align__(16) _Float16 hA[2][5][512];
    int b0 = bid * 16;
    int w = tid >> 6, l = tid & 63;
    const _Float16* BpW = BpE + w * 10240 + l * 8;
    for (int i = tid; i < 5120; i += 640) ((_Float16*)hA)[i] = (_Float16)0.f;
    float cst[4] = {0.f, 0.f, 0.f, 0.f};
    int row0 = 4 * (l >> 4);
    int u = 16 * w + (l & 15);
    int kloc = u & 31, tile = u >> 5;
    int wl2 = row0 | ((kloc >> 3) << 4);
    const float* gpb = gx0p + ((long)(b0 + row0) * 128) * 640 + w * 64 + (l & 15);
    v8h Ba[4], Bb[4];
    Ba[0] = *(const v8h*)(BpW + 0);
    Ba[1] = *(const v8h*)(BpW + 512);
    Ba[2] = *(const v8h*)(BpW + 1024);
    Ba[3] = *(const v8h*)(BpW + 1536);
    v4f xv0, xv1, xv2, xv3, xn0, xn1, xn2, xn3;
    #pragma unroll
    for (int reg = 0; reg < 4; ++reg) {
        xv0[reg] = gpb[(long)reg * 81920 + 0];
        xv1[reg] = gpb[(long)reg * 81920 + 16];
        xv2[reg] = gpb[(long)reg * 81920 + 32];
        xv3[reg] = gpb[(long)reg * 81920 + 48];
    }
    xn0 = xv0; xn1 = xv1; xn2 = xv2; xn3 = xv3;
    barrier_lds();
    #define XPRE_E(S_)                                                      \
        if ((S_) + 1 < 128) {                                               \
            const float* gp_ = gpb + (long)((S_) + 1) * 640;                \
            _Pragma("unroll")                                               \
            for (int reg = 0; reg < 4; ++reg) {                             \
                xn0[reg] = gp_[(long)reg * 81920 + 0];                      \
                xn1[reg] = gp_[(long)reg * 81920 + 16];                     \
                xn2[reg] = gp_[(long)reg * 81920 + 32];                     \
                xn3[reg] = gp_[(long)reg * 81920 + 48];                     \
            }                                                               \
        }
    #define HST_E(S_)                                                       \
        if ((S_) == 127 && u < 150) h_end[(b0 + row0 + reg) * 300 + u] = h;
    #pragma unroll 1
    for (int s2 = 0; s2 < 64; ++s2) {
        int s = 2 * s2;
        MSTEP(Ba, Bb, 0, s, XPRE_E(s), HST_E(s))
        MSTEP(Bb, Ba, 1, s + 1, XPRE_E(s + 1), HST_E(s + 1))
    }
    #undef XPRE_E
    #undef HST_E
}

// ---------------- MFMA-batched decoder LSTM (v2) ----------------
// grid 16: dir = bid>>3, b0 = (bid&7)*16. x from gxd fp16; writes decH fp16.
__global__ __launch_bounds__(640) void k_declstm_m(
    const _Float16* __restrict__ gxd, const _Float16* __restrict__ BpD,
    _Float16* __restrict__ decH) {
    __shared__ __align__(16) _Float16 hA[2][5][512];
    int bid = blockIdx.x, tid = threadIdx.x;
    int dirv = bid >> 3, b0 = (bid & 7) * 16;
    int w = tid >> 6, l = tid & 63;
    const _Float16* BpW = BpD + (long)dirv * 102400 + w * 10240 + l * 8;
    for (int i = tid; i < 5120; i += 640) ((_Float16*)hA)[i] = (_Float16)0.f;
    float cst[4] = {0.f, 0.f, 0.f, 0.f};
    int row0 = 4 * (l >> 4);
    int u = 16 * w + (l & 15);
    int kloc = u & 31, tile = u >> 5;
    int wl2 = row0 | ((kloc >> 3) << 4);
    const _Float16* gpbH = gxd + ((long)(dirv * 128 + b0 + row0) * 128) * 640 + w * 64 + (l & 15);
    v8h Ba[4], Bb[4];
    Ba[0] = *(const v8h*)(BpW + 0);
    Ba[1] = *(const v8h*)(BpW + 512);
    Ba[2] = *(const v8h*)(BpW + 1024);
    Ba[3] = *(const v8h*)(BpW + 1536);
    v4f xv0, xv1, xv2, xv3, xn0, xn1, xn2, xn3;
    {
        int t0 = dirv ? 127 : 0;
        const _Float16* gp_ = gpbH + (long)t0 * 640;
        #pragma unroll
        for (int reg = 0; reg < 4; ++reg) {
            xv0[reg] = (float)gp_[(long)reg * 81920 + 0];
            xv1[reg] = (float)gp_[(long)reg * 81920 + 16];
            xv2[reg] = (float)gp_[(long)reg * 81920 + 32];
            xv3[reg] = (float)gp_[(long)reg * 81920 + 48];
        }
    }
    xn0 = xv0; xn1 = xv1; xn2 = xv2; xn3 = xv3;
    barrier_lds();
    #define XPRE_D(S_)                                                      \
        if ((S_) + 1 < 128) {                                               \
            int tn_ = dirv ? (126 - (S_)) : ((S_) + 1);                     \
            const _Float16* gp_ = gpbH + (long)tn_ * 640;                   \
            _Pragma("unroll")                                               \
            for (int reg = 0; reg < 4; ++reg) {                             \
                xn0[reg] = (float)gp_[(long)reg * 81920 + 0];               \
                xn1[reg] = (float)gp_[(long)reg * 81920 + 16];              \
                xn2[reg] = (float)gp_[(long)reg * 81920 + 32];              \
                xn3[reg] = (float)gp_[(long)reg * 81920 + 48];              \
            }                                                               \
        }
    #define HST_D(S_)                                                       \
        {                                                                   \
            int t_ = dirv ? (127 - (S_)) : (S_);                            \
            if (u < 150)                                                    \
                decH[((b0 + row0 + reg) * 128 + t_) * 300 + dirv * 150 + u] = (_Float16)h; \
        }
    #pragma unroll 1
    for (int s2 = 0; s2 < 64; ++s2) {
        int s = 2 * s2;
        MSTEP(Ba, Bb, 0, s, XPRE_D(s), HST_D(s))
        MSTEP(Bb, Ba, 1, s + 1, XPRE_D(s + 1), HST_D(s + 1))
    }
    #undef XPRE_D
    #undef HST_D
}

// ---------------- final: out = dec(fp16) @ fc_w^T + fc_b, fp16 dot2 ----------------
__global__ __launch_bounds__(256) void k_fingemm(const _Float16* __restrict__ decH,
                                                 const float* __restrict__ fw,
                                                 const float* __restrict__ fb,
                                                 float* __restrict__ out) {
    __shared__ __align__(16) unsigned AsT[16 * 68];
    __shared__ __align__(16) unsigned FwT[16 * 68];
    int r0 = blockIdx.x * 64, tid = threadIdx.x;
    int ty = tid >> 4, tx = tid & 15;
    float acc[4][4];
    #pragma unroll
    for (int r = 0; r < 4; ++r)
        #pragma unroll
        for (int c = 0; c < 4; ++c) acc[r][c] = 0.f;
    for (int kc = 0; kc < 10; ++kc) {
        int k0 = kc * 32;
        for (int f = tid; f < 1024; f += 256) {
            int m = f >> 4, kk2 = f & 15;
            int k = k0 + kk2 * 2;
            AsT[kk2 * 68 + m] =
                (k + 1 < 300) ? *(const unsigned*)&decH[(r0 + m) * 300 + k] : 0u;
        }
        for (int f = tid; f < 1024; f += 256) {
            int n = f >> 4, kk2 = f & 15;
            int k = k0 + kk2 * 2;
            FwT[kk2 * 68 + n] =
                (k + 1 < 300) ? pku(fw[n * 300 + k], fw[n * 300 + k + 1]) : 0u;
        }
        __syncthreads();
        #pragma unroll 4
        for (int kk2 = 0; kk2 < 16; ++kk2) {
            uint4 a4 = *(const uint4*)&AsT[kk2 * 68 + ty * 4];
            uint4 w4 = *(const uint4*)&FwT[kk2 * 68 + tx * 4];
            v2h a0 = upk(a4.x), a1 = upk(a4.y), a2 = upk(a4.z), a3 = upk(a4.w);
            v2h w0 = upk(w4.x), w1 = upk(w4.y), w2 = upk(w4.z), w3 = upk(w4.w);
            acc[0][0] = fdot2(a0, w0, acc[0][0]); acc[0][1] = fdot2(a0, w1, acc[0][1]);
            acc[0][2] = fdot2(a0, w2, acc[0][2]); acc[0][3] = fdot2(a0, w3, acc[0][3]);
            acc[1][0] = fdot2(a1, w0, acc[1][0]); acc[1][1] = fdot2(a1, w1, acc[1][1]);
            acc[1][2] = fdot2(a1, w2, acc[1][2]); acc[1][3] = fdot2(a1, w3, acc[1][3]);
            acc[2][0] = fdot2(a2, w0, acc[2][0]); acc[2][1] = fdot2(a2, w1, acc[2][1]);
            acc[2][2] = fdot2(a2, w2, acc[2][2]); acc[2][3] = fdot2(a2, w3, acc[2][3]);
            acc[3][0] = fdot2(a3, w0, acc[3][0]); acc[3][1] = fdot2(a3, w1, acc[3][1]);
            acc[3][2] = fdot2(a3, w2, acc[3][2]); acc[3][3] = fdot2(a3, w3, acc[3][3]);
        }
        __syncthreads();
    }
    for (int r = 0; r < 4; ++r) {
        int m = r0 + ty * 4 + r;
        float4 o4;
        o4.x = acc[r][0] + fb[tx * 4 + 0];
        o4.y = acc[r][1] + fb[tx * 4 + 1];
        o4.z = acc[r][2] + fb[tx * 4 + 2];
        o4.w = acc[r][3] + fb[tx * 4 + 3];
        *(float4*)&out[m * 64 + tx * 4] = o4;
    }
}

// ---------------- host launcher ----------------
extern "C" void kernel_launch(void* const* d_in, const int* in_sizes, int n_in,
                              void* d_out, int out_size, void* d_ws, size_t ws_size,
                              hipStream_t stream) {
    const float* x = (const float*)d_in[0];
    const float* c2w = (const float*)d_in[3];
    const float* c2b = (const float*)d_in[4];
    const float* c3w = (const float*)d_in[5];
    const float* c3b = (const float*)d_in[6];
    const float* gatw = (const float*)d_in[7];
    const float* gatas = (const float*)d_in[8];
    const float* gatad = (const float*)d_in[9];
    const float* gatb = (const float*)d_in[10];
    const float* gcnw = (const float*)d_in[11];
    const float* gcnb = (const float*)d_in[12];
    const float* lwih = (const float*)d_in[13];
    const float* lwhh = (const float*)d_in[14];
    const float* lbih = (const float*)d_in[15];
    const float* lbhh = (const float*)d_in[16];
    const float* dwih = (const float*)d_in[17];
    const float* dwhh = (const float*)d_in[18];
    const float* dbih = (const float*)d_in[19];
    const float* dbhh = (const float*)d_in[20];
    const float* fcw = (const float*)d_in[21];
    const float* fcb = (const float*)d_in[22];
    float* out = (float*)d_out;
    float* ws = (float*)d_ws;

    float* hs0 = ws;                          // 1,048,576
    float* hs1 = ws + 1048576;                // 1,048,576
    float* hs2 = ws + 2097152;                // 1,048,576
    float* gx0p = ws + 3145728;               // 10,485,760 (128*128*640)
    float* gx1 = ws + 13631488;               // 76,800
    float* hend = ws + 13708288;              // 38,400
    float* PT = ws + 13746688;                // 361,200
    _Float16* decH = (_Float16*)(ws + 14107888);   // 4,915,200 halfs (2,457,600 f)
    _Float16* BpE = (_Float16*)(ws + 16565488);    // 102,400 halfs (51,200 f)
    _Float16* BpD = (_Float16*)(ws + 16616688);    // 204,800 halfs (102,400 f)
    float* PD = hs0;                          // overlays hs0 (dead after encgemm/encgx1)
    _Float16* gxd = (_Float16*)gx0p;          // overlays gx0p (dead after enc LSTM)

    k_prepB<<<400, 256, 0, stream>>>(lwhh, BpE, 1);
    k_prepB<<<800, 256, 0, stream>>>(dwhh, BpD, 2);
    k_copy<<<1024, 256, 0, stream>>>(x, hs0);
    k_conv2<<<dim3(128, 2, 2), 256, (70 * 68 + 7 * 16 * 256) * 4, stream>>>(
        x, c2w, c2b, c3w, c3b, hs1, hs2);
    for (int l = 0; l < 2; ++l)
        k_stgat<<<dim3(128, 3), 256, 77824, stream>>>(hs0, hs1, hs2, gatw, gatas,
                                                      gatad, gatb, gcnw, gcnb, l);
    k_encgemm2<<<dim3(128, 5), 256, 0, stream>>>(hs0, hs1, hs2, lwih, lbih, lbhh, gx0p);
    k_zpad<<<2560, 256, 0, stream>>>(gx0p);
    k_encgx1<<<128, 256, 0, stream>>>(hs0, hs1, hs2, lwih, lbih, lbhh, gx1);
    k_ptpref<<<5, 256, 0, stream>>>(dwih, PT);
    k_pd<<<600, 256, 0, stream>>>(PT, PD);   // hs0 region now dead
    k_enclstm_m<<<136, 640, 0, stream>>>(gx0p, gx1, BpE, hend);
    k_gxd<<<256, 256, 0, stream>>>(PD, hend, dbih, dbhh, gxd);   // gx0p region now dead
    k_declstm_m<<<16, 640, 0, stream>>>(gxd, BpD, decH);
    k_fingemm<<<256, 256, 0, stream>>>(decH, fcw, fcb, out);
}

// Round 13
// 543.039 us; speedup vs baseline: 1.9287x; 1.8731x over previous
//
#include <hip/hip_runtime.h>
#include <hip/hip_fp16.h>

// ---------------- model dims ----------------
// B=128, W=128, N=64, HID=150, L=2
// gates = 4*HID = 600 ; enc input D = 3*N = 192 ; dec input = 2*HID = 300
//
// LSTM design note (R5-R12): the 640-thread quad-gate scan layout (76 weight
// VGPRs/thread, VGPR_Count=84) is the proven optimum on this toolchain. The
// compiler hard-caps VGPR allocation at 128 (4-wave scheduler target) and
// silently spills past it — launch_bounds min-waves, amdgpu_waves_per_eu,
// and macro-ized array access all fail to unlock more. MFMA-batched LSTM
// (R11/R12) is latency-bound at 1-2% occupancy: B-frags can't stay register-
// resident (>128 cap) nor LDS-resident (200KB/block), and a 1-stage prefetch
// ring covers <20% of the L2 latency. Do not revisit without a new compiler.

typedef _Float16 v2h __attribute__((ext_vector_type(2)));

__device__ __forceinline__ float sigm(float x) {
    return 1.0f / (1.0f + __expf(-x));
}
__device__ __forceinline__ float tanhfast(float x) {
    return 2.0f / (1.0f + __expf(-2.0f * x)) - 1.0f;
}
__device__ __forceinline__ v2h pk2(float a, float b) {
    v2h r; r[0] = (_Float16)a; r[1] = (_Float16)b; return r;
}
__device__ __forceinline__ unsigned pku(float a, float b) {
    return __builtin_bit_cast(unsigned, pk2(a, b));
}
__device__ __forceinline__ v2h upk(unsigned u) { return __builtin_bit_cast(v2h, u); }
__device__ __forceinline__ float fdot2(v2h a, v2h b, float c) {
#if __has_builtin(__builtin_amdgcn_fdot2)
    return __builtin_amdgcn_fdot2(a, b, c, false);
#else
    return c + (float)a[0] * (float)b[0] + (float)a[1] * (float)b[1];
#endif
}

// LDS-only workgroup barrier (orders ds ops; leaves global loads in flight).
__device__ __forceinline__ void barrier_lds() {
    asm volatile("s_waitcnt lgkmcnt(0)" ::: "memory");
    __builtin_amdgcn_s_barrier();
}

// ---------------- copy x -> hs0 ----------------
__global__ void k_copy(const float* __restrict__ x, float* __restrict__ hs0) {
    int i = blockIdx.x * 256 + threadIdx.x;           // 262144 float4
    ((float4*)hs0)[i] = ((const float4*)x)[i];
}

// ---------------- conv branches (merged) ----------------
__global__ __launch_bounds__(256) void k_conv2(
    const float* __restrict__ x,
    const float* __restrict__ cw5, const float* __restrict__ cb5,
    const float* __restrict__ cw7, const float* __restrict__ cb7,
    float* __restrict__ hs1, float* __restrict__ hs2) {
    extern __shared__ float S[];
    float* xt = S;              // [70][68]
    float* wl = S + 70 * 68;    // [(t*16+i4)*256 + o*4 + j]
    int b = blockIdx.x, wh = blockIdx.y, br = blockIdx.z;
    int K = br ? 7 : 5;
    const float* cw = br ? cw7 : cw5;
    const float* cb = br ? cb7 : cb5;
    float* dst = br ? hs2 : hs1;
    int w0 = wh * 64;
    int tid = threadIdx.x;

    for (int f = tid; f < 70 * 64; f += 256) {
        int ww = f >> 6, i = f & 63;
        int wp = w0 - 3 + ww;
        xt[ww * 68 + i] = ((unsigned)wp < 128u) ? x[b * 8192 + wp * 64 + i] : 0.f;
    }
    int nw = K * 4096;
    for (int f = tid; f < nw; f += 256) {
        int j = f & 3, o = (f >> 2) & 63, i4 = (f >> 8) & 15, t = f >> 12;
        wl[f] = cw[(o * 64 + i4 * 4 + j) * K + t];
    }
    __syncthreads();

    int to = tid & 15, tw = tid >> 4;
    float acc[4][4] = {};
    int ob = 3 - (K >> 1);
    for (int t = 0; t < K; ++t) {
        int rbase = tw * 4 + t + ob;
        for (int i4 = 0; i4 < 16; ++i4) {
            float4 a0 = *(const float4*)&xt[(rbase + 0) * 68 + i4 * 4];
            float4 a1 = *(const float4*)&xt[(rbase + 1) * 68 + i4 * 4];
            float4 a2 = *(const float4*)&xt[(rbase + 2) * 68 + i4 * 4];
            float4 a3 = *(const float4*)&xt[(rbase + 3) * 68 + i4 * 4];
            const float* wrow = &wl[(t * 16 + i4) * 256];
            float4 b0 = *(const float4*)&wrow[to * 4];
            float4 b1 = *(const float4*)&wrow[(to + 16) * 4];
            float4 b2 = *(const float4*)&wrow[(to + 32) * 4];
            float4 b3 = *(const float4*)&wrow[(to + 48) * 4];
            #define DOT4(w_, a_) \
                acc[w_][0] = fmaf(a_.x, b0.x, acc[w_][0]); acc[w_][0] = fmaf(a_.y, b0.y, acc[w_][0]); \
                acc[w_][0] = fmaf(a_.z, b0.z, acc[w_][0]); acc[w_][0] = fmaf(a_.w, b0.w, acc[w_][0]); \
                acc[w_][1] = fmaf(a_.x, b1.x, acc[w_][1]); acc[w_][1] = fmaf(a_.y, b1.y, acc[w_][1]); \
                acc[w_][1] = fmaf(a_.z, b1.z, acc[w_][1]); acc[w_][1] = fmaf(a_.w, b1.w, acc[w_][1]); \
                acc[w_][2] = fmaf(a_.x, b2.x, acc[w_][2]); acc[w_][2] = fmaf(a_.y, b2.y, acc[w_][2]); \
                acc[w_][2] = fmaf(a_.z, b2.z, acc[w_][2]); acc[w_][2] = fmaf(a_.w, b2.w, acc[w_][2]); \
                acc[w_][3] = fmaf(a_.x, b3.x, acc[w_][3]); acc[w_][3] = fmaf(a_.y, b3.y, acc[w_][3]); \
                acc[w_][3] = fmaf(a_.z, b3.z, acc[w_][3]); acc[w_][3] = fmaf(a_.w, b3.w, acc[w_][3]);
            DOT4(0, a0)
            DOT4(1, a1)
            DOT4(2, a2)
            DOT4(3, a3)
            #undef DOT4
        }
    }
    #pragma unroll
    for (int wj = 0; wj < 4; ++wj) {
        int w = w0 + tw * 4 + wj;
        #pragma unroll
        for (int oj = 0; oj < 4; ++oj) {
            int o = to + 16 * oj;
            dst[b * 8192 + w * 64 + o] = fmaxf(acc[wj][oj] + cb[o], 0.f);
        }
    }
}

// ---------------- one STGAT layer (all 3 branches), fp16 dot2, in-place residual ----------------
// grid (128 b, 3 br), block 256, dyn LDS 77824 B -> 2 blocks/CU
__global__ __launch_bounds__(256, 2) void k_stgat(
    float* __restrict__ hs0, float* __restrict__ hs1, float* __restrict__ hs2,
    const float* __restrict__ gat_w, const float* __restrict__ gat_asrc,
    const float* __restrict__ gat_adst, const float* __restrict__ gat_b,
    const float* __restrict__ gcn_w, const float* __restrict__ gcn_b, int l) {
    extern __shared__ float S[];
    _Float16* Sh = (_Float16*)S;
    const int XHh = 0;           // xp fp16 [64 n][132 w]
    const int GHh = 8448;        // gw fp16 [128 wo][132 k]
    const int HHTh = 25344;      // h^T fp16 [128 wo][68 n]
    const int AHh = 34560;       // A fp16 [64 j][68 i]
    const int FHh = 8448;        // f^T fp16 [128 w][68 n]
    const int CHh = 0;           // cw fp16 [64 c][68 k]
    const int SDo = 17024;       // s[64], d[64]
    const int CSo = 17024;       // chunk sums [4][64]
    const int HGo = 8576;        // hg fp32 [128 w][66 c]

    int b = blockIdx.x, br = blockIdx.y, tid = threadIdx.x;
    float* hs = (br == 0 ? hs0 : (br == 1 ? hs1 : hs2)) + b * 8192;
    int wsel = br * 2 + l;
    const float* gw = gat_w + wsel * 16384;
    const float* asr = gat_asrc + wsel * 128;
    const float* ads = gat_adst + wsel * 128;
    const float* gb = gat_b + wsel * 128;
    const float* cwp = gcn_w + wsel * 4096;
    const float* cbp = gcn_b + wsel * 64;

    {
        const float4* hsv = (const float4*)hs;
        for (int mt = tid; mt < 512; mt += 256) {
            int ng = mt & 15, wg = mt >> 4;
            float4 r0 = hsv[(wg * 4 + 0) * 16 + ng];
            float4 r1 = hsv[(wg * 4 + 1) * 16 + ng];
            float4 r2 = hsv[(wg * 4 + 2) * 16 + ng];
            float4 r3 = hsv[(wg * 4 + 3) * 16 + ng];
            int n0 = ng * 4, ww = wg * 4;
            *(uint2*)&Sh[XHh + (n0 + 0) * 132 + ww] = make_uint2(pku(r0.x, r1.x), pku(r2.x, r3.x));
            *(uint2*)&Sh[XHh + (n0 + 1) * 132 + ww] = make_uint2(pku(r0.y, r1.y), pku(r2.y, r3.y));
            *(uint2*)&Sh[XHh + (n0 + 2) * 132 + ww] = make_uint2(pku(r0.z, r1.z), pku(r2.z, r3.z));
            *(uint2*)&Sh[XHh + (n0 + 3) * 132 + ww] = make_uint2(pku(r0.w, r1.w), pku(r2.w, r3.w));
        }
        const float4* gwv = (const float4*)gw;
        for (int f4 = tid; f4 < 4096; f4 += 256) {
            float4 v = gwv[f4];
            int wo = f4 >> 5, k4 = f4 & 31;
            *(uint2*)&Sh[GHh + wo * 132 + k4 * 4] = make_uint2(pku(v.x, v.y), pku(v.z, v.w));
        }
    }
    __syncthreads();

    int wq = tid & 15, nq = tid >> 4;
    {
        float asv[8], adv[8];
        #pragma unroll
        for (int c = 0; c < 8; ++c) { asv[c] = asr[wq + 16 * c]; adv[c] = ads[wq + 16 * c]; }
        float acc0[8] = {}, acc1[8] = {}, acc2[8] = {}, acc3[8] = {};
        const _Float16* Arow = Sh + XHh + nq * 4 * 132;
        const _Float16* Brow = Sh + GHh + wq * 132;
        for (int k4 = 0; k4 < 32; ++k4) {
            uint2 u0 = *(const uint2*)&Arow[k4 * 4];
            uint2 u1 = *(const uint2*)&Arow[132 + k4 * 4];
            uint2 u2 = *(const uint2*)&Arow[264 + k4 * 4];
            uint2 u3 = *(const uint2*)&Arow[396 + k4 * 4];
            v2h a0l = upk(u0.x), a0h = upk(u0.y), a1l = upk(u1.x), a1h = upk(u1.y);
            v2h a2l = upk(u2.x), a2h = upk(u2.y), a3l = upk(u3.x), a3h = upk(u3.y);
            #pragma unroll
            for (int c = 0; c < 8; ++c) {
                uint2 ub = *(const uint2*)&Brow[c * (16 * 132) + k4 * 4];
                v2h bl = upk(ub.x), bh = upk(ub.y);
                acc0[c] = fdot2(a0l, bl, acc0[c]); acc0[c] = fdot2(a0h, bh, acc0[c]);
                acc1[c] = fdot2(a1l, bl, acc1[c]); acc1[c] = fdot2(a1h, bh, acc1[c]);
                acc2[c] = fdot2(a2l, bl, acc2[c]); acc2[c] = fdot2(a2h, bh, acc2[c]);
                acc3[c] = fdot2(a3l, bl, acc3[c]); acc3[c] = fdot2(a3h, bh, acc3[c]);
            }
        }
        #pragma unroll
        for (int c = 0; c < 8; ++c)
            *(uint2*)&Sh[HHTh + (wq + 16 * c) * 68 + nq * 4] =
                make_uint2(pku(acc0[c], acc1[c]), pku(acc2[c], acc3[c]));
        float ps0 = 0, ps1 = 0, ps2 = 0, ps3 = 0, pd0 = 0, pd1 = 0, pd2 = 0, pd3 = 0;
        #pragma unroll
        for (int c = 0; c < 8; ++c) {
            ps0 = fmaf(acc0[c], asv[c], ps0); ps1 = fmaf(acc1[c], asv[c], ps1);
            ps2 = fmaf(acc2[c], asv[c], ps2); ps3 = fmaf(acc3[c], asv[c], ps3);
            pd0 = fmaf(acc0[c], adv[c], pd0); pd1 = fmaf(acc1[c], adv[c], pd1);
            pd2 = fmaf(acc2[c], adv[c], pd2); pd3 = fmaf(acc3[c], adv[c], pd3);
        }
        #pragma unroll
        for (int m = 1; m < 16; m <<= 1) {
            ps0 += __shfl_xor(ps0, m); ps1 += __shfl_xor(ps1, m);
            ps2 += __shfl_xor(ps2, m); ps3 += __shfl_xor(ps3, m);
            pd0 += __shfl_xor(pd0, m); pd1 += __shfl_xor(pd1, m);
            pd2 += __shfl_xor(pd2, m); pd3 += __shfl_xor(pd3, m);
        }
        if (wq == 0) {
            S[SDo + nq * 4 + 0] = ps0; S[SDo + nq * 4 + 1] = ps1;
            S[SDo + nq * 4 + 2] = ps2; S[SDo + nq * 4 + 3] = ps3;
            S[SDo + 64 + nq * 4 + 0] = pd0; S[SDo + 64 + nq * 4 + 1] = pd1;
            S[SDo + 64 + nq * 4 + 2] = pd2; S[SDo + 64 + nq * 4 + 3] = pd3;
        }
    }
    __syncthreads();

    {
        const float4* cwv = (const float4*)cwp;
        for (int f4 = tid; f4 < 1024; f4 += 256) {
            float4 v = cwv[f4];
            int c = f4 >> 4, k4 = f4 & 15;
            *(uint2*)&Sh[CHh + c * 68 + k4 * 4] = make_uint2(pku(v.x, v.y), pku(v.z, v.w));
        }
        if (tid < 64) {
            int j = tid;
            float dj = S[SDo + 64 + j];
            float mx = -1e30f;
            for (int i = 0; i < 64; ++i) {
                float e = S[SDo + i] + dj;
                e = (e > 0.f) ? e : 0.2f * e;
                mx = fmaxf(mx, e);
            }
            float sum = 0.f;
            for (int i = 0; i < 64; i += 2) {
                float e0 = S[SDo + i] + dj;     e0 = (e0 > 0.f) ? e0 : 0.2f * e0;
                float e1 = S[SDo + i + 1] + dj; e1 = (e1 > 0.f) ? e1 : 0.2f * e1;
                float x0 = __expf(e0 - mx), x1 = __expf(e1 - mx);
                sum += x0 + x1;
                *(unsigned*)&Sh[AHh + j * 68 + i] = pku(x0, x1);
            }
            float rinv = 1.f / sum;
            for (int i = 0; i < 64; i += 2) {
                v2h v = upk(*(const unsigned*)&Sh[AHh + j * 68 + i]);
                *(unsigned*)&Sh[AHh + j * 68 + i] = pku((float)v[0] * rinv, (float)v[1] * rinv);
            }
        }
    }
    __syncthreads();

    {
        float gbv[8];
        #pragma unroll
        for (int c = 0; c < 8; ++c) gbv[c] = gb[wq + 16 * c];
        float acc0[8] = {}, acc1[8] = {}, acc2[8] = {}, acc3[8] = {};
        const _Float16* Arow = Sh + AHh + nq * 4 * 68;
        const _Float16* Brow = Sh + HHTh + wq * 68;
        for (int k4 = 0; k4 < 16; ++k4) {
            uint2 u0 = *(const uint2*)&Arow[k4 * 4];
            uint2 u1 = *(const uint2*)&Arow[68 + k4 * 4];
            uint2 u2 = *(const uint2*)&Arow[136 + k4 * 4];
            uint2 u3 = *(const uint2*)&Arow[204 + k4 * 4];
            v2h a0l = upk(u0.x), a0h = upk(u0.y), a1l = upk(u1.x), a1h = upk(u1.y);
            v2h a2l = upk(u2.x), a2h = upk(u2.y), a3l = upk(u3.x), a3h = upk(u3.y);
            #pragma unroll
            for (int c = 0; c < 8; ++c) {
                uint2 ub = *(const uint2*)&Brow[c * (16 * 68) + k4 * 4];
                v2h bl = upk(ub.x), bh = upk(ub.y);
                acc0[c] = fdot2(a0l, bl, acc0[c]); acc0[c] = fdot2(a0h, bh, acc0[c]);
                acc1[c] = fdot2(a1l, bl, acc1[c]); acc1[c] = fdot2(a1h, bh, acc1[c]);
                acc2[c] = fdot2(a2l, bl, acc2[c]); acc2[c] = fdot2(a2h, bh, acc2[c]);
                acc3[c] = fdot2(a3l, bl, acc3[c]); acc3[c] = fdot2(a3h, bh, acc3[c]);
            }
        }
        #pragma unroll
        for (int c = 0; c < 8; ++c) {
            float f0 = fmaxf(acc0[c] + gbv[c], 0.f);
            float f1 = fmaxf(acc1[c] + gbv[c], 0.f);
            float f2 = fmaxf(acc2[c] + gbv[c], 0.f);
            float f3 = fmaxf(acc3[c] + gbv[c], 0.f);
            *(uint2*)&Sh[FHh + (wq + 16 * c) * 68 + nq * 4] = make_uint2(pku(f0, f1), pku(f2, f3));
        }
    }
    __syncthreads();

    {
        int cq = tid & 7, wg = tid >> 3;
        float acc0[8] = {}, acc1[8] = {}, acc2[8] = {}, acc3[8] = {};
        const _Float16* Arow = Sh + FHh + wg * 4 * 68;
        const _Float16* Brow = Sh + CHh + cq * 68;
        for (int k4 = 0; k4 < 16; ++k4) {
            uint2 u0 = *(const uint2*)&Arow[k4 * 4];
            uint2 u1 = *(const uint2*)&Arow[68 + k4 * 4];
            uint2 u2 = *(const uint2*)&Arow[136 + k4 * 4];
            uint2 u3 = *(const uint2*)&Arow[204 + k4 * 4];
            v2h a0l = upk(u0.x), a0h = upk(u0.y), a1l = upk(u1.x), a1h = upk(u1.y);
            v2h a2l = upk(u2.x), a2h = upk(u2.y), a3l = upk(u3.x), a3h = upk(u3.y);
            #pragma unroll
            for (int cc = 0; cc < 8; ++cc) {
                uint2 ub = *(const uint2*)&Brow[cc * (8 * 68) + k4 * 4];
                v2h bl = upk(ub.x), bh = upk(ub.y);
                acc0[cc] = fdot2(a0l, bl, acc0[cc]); acc0[cc] = fdot2(a0h, bh, acc0[cc]);
                acc1[cc] = fdot2(a1l, bl, acc1[cc]); acc1[cc] = fdot2(a1h, bh, acc1[cc]);
                acc2[cc] = fdot2(a2l, bl, acc2[cc]); acc2[cc] = fdot2(a2h, bh, acc2[cc]);
                acc3[cc] = fdot2(a3l, bl, acc3[cc]); acc3[cc] = fdot2(a3h, bh, acc3[cc]);
            }
        }
        #pragma unroll
        for (int cc = 0; cc < 8; ++cc) {
            int c = cq + 8 * cc;
            S[HGo + (wg * 4 + 0) * 66 + c] = acc0[cc];
            S[HGo + (wg * 4 + 1) * 66 + c] = acc1[cc];
            S[HGo + (wg * 4 + 2) * 66 + c] = acc2[cc];
            S[HGo + (wg * 4 + 3) * 66 + c] = acc3[cc];
        }
    }
    __syncthreads();

    {
        int c = tid & 63, q = tid >> 6;
        float local = 0.f;
        for (int i = 0; i < 32; ++i) {
            int w = q * 32 + i;
            local = fmaf(rsqrtf((float)(w + 1)), S[HGo + w * 66 + c], local);
        }
        S[CSo + q * 64 + c] = local;
    }
    __syncthreads();
    {
        int c = tid & 63, q = tid >> 6;
        float run = 0.f;
        for (int qq = 0; qq < q; ++qq) run += S[CSo + qq * 64 + c];
        float cbv = cbp[c];
        for (int i = 0; i < 32; ++i) {
            int w = q * 32 + i;
            float dv = rsqrtf((float)(w + 1));
            run = fmaf(dv, S[HGo + w * 66 + c], run);
            S[HGo + w * 66 + c] = fmaxf(fmaf(dv, run, cbv), 0.f);
        }
    }
    __syncthreads();

    {
        float4* hsv4 = (float4*)hs;
        for (int f4 = tid; f4 < 2048; f4 += 256) {
            int a = f4 >> 4, cc0 = (f4 & 15) * 4;
            float4 old = hsv4[f4];
            int n = a & 63, ahi = a >> 6;
            old.x += S[HGo + (cc0 * 2 + ahi) * 66 + n];
            old.y += S[HGo + ((cc0 + 1) * 2 + ahi) * 66 + n];
            old.z += S[HGo + ((cc0 + 2) * 2 + ahi) * 66 + n];
            old.w += S[HGo + ((cc0 + 3) * 2 + ahi) * 66 + n];
            hsv4[f4] = old;
        }
    }
}

// ---------------- encoder input GEMM (dir0 full), fp16 dot2 ----------------
// grid (128 b, 5 gy), block 256. Block tile 128t x 128g, thread tile 8x8.
// LDS rows padded to 72 halfwords; 16B chunks XOR-swizzled by (row>>3)&7.
__global__ __launch_bounds__(256) void k_encgemm2(
    const float* __restrict__ hs0, const float* __restrict__ hs1, const float* __restrict__ hs2,
    const float* __restrict__ wih, const float* __restrict__ bih, const float* __restrict__ bhh,
    float* __restrict__ gx0) {
    __shared__ __align__(16) _Float16 Xh[128 * 72];
    __shared__ __align__(16) _Float16 Wh[128 * 72];
    int b = blockIdx.x, gy = blockIdx.y, tid = threadIdx.x;
    int g0 = gy * 128;
    int ty = tid >> 4, tx = tid & 15;     // 16 t-groups x 16 g-groups, 8x8 each
    float acc[8][8];
    #pragma unroll
    for (int i = 0; i < 8; ++i)
        #pragma unroll
        for (int j = 0; j < 8; ++j) acc[i][j] = 0.f;
    const float* hsb[3] = {hs0 + b * 8192, hs1 + b * 8192, hs2 + b * 8192};

    for (int c = 0; c < 3; ++c) {
        const float4* src = (const float4*)hsb[c];
        for (int f = tid; f < 2048; f += 256) {
            int t = f >> 4, k4 = f & 15;
            float4 v = src[f];
            int pos = (((k4 >> 1) ^ ((t >> 3) & 7)) << 1) + (k4 & 1);
            *(uint2*)&Xh[t * 72 + pos * 4] = make_uint2(pku(v.x, v.y), pku(v.z, v.w));
        }
        for (int f = tid; f < 2048; f += 256) {
            int g = f >> 4, k4 = f & 15;
            int gg = g0 + g;
            float4 v = (gg < 600) ? *(const float4*)&wih[gg * 192 + c * 64 + k4 * 4]
                                  : make_float4(0.f, 0.f, 0.f, 0.f);
            int pos = (((k4 >> 1) ^ ((g >> 3) & 7)) << 1) + (k4 & 1);
            *(uint2*)&Wh[g * 72 + pos * 4] = make_uint2(pku(v.x, v.y), pku(v.z, v.w));
        }
        __syncthreads();
        #pragma unroll
        for (int k8 = 0; k8 < 8; ++k8) {
            uint4 av[8];
            #pragma unroll
            for (int i = 0; i < 8; ++i) {
                int row = ty * 8 + i;
                av[i] = *(const uint4*)&Xh[row * 72 + (k8 ^ ((row >> 3) & 7)) * 8];
            }
            #pragma unroll
            for (int j = 0; j < 8; ++j) {
                int row = tx * 8 + j;
                uint4 bv = *(const uint4*)&Wh[row * 72 + (k8 ^ ((row >> 3) & 7)) * 8];
                v2h b0 = upk(bv.x), b1 = upk(bv.y), b2 = upk(bv.z), b3 = upk(bv.w);
                #pragma unroll
                for (int i = 0; i < 8; ++i) {
                    acc[i][j] = fdot2(upk(av[i].x), b0, acc[i][j]);
                    acc[i][j] = fdot2(upk(av[i].y), b1, acc[i][j]);
                    acc[i][j] = fdot2(upk(av[i].z), b2, acc[i][j]);
                    acc[i][j] = fdot2(upk(av[i].w), b3, acc[i][j]);
                }
            }
        }
        __syncthreads();
    }
    // epilogue: + bias, store fp32
    #pragma unroll
    for (int i = 0; i < 8; ++i) {
        int t = ty * 8 + i;
        float* orow = gx0 + (b * 128 + t) * 600;
        #pragma unroll
        for (int jj = 0; jj < 2; ++jj) {
            int gbase = g0 + tx * 8 + jj * 4;
            if (gbase + 3 < 600) {
                float4 o;
                o.x = acc[i][jj * 4 + 0] + bih[gbase + 0] + bhh[gbase + 0];
                o.y = acc[i][jj * 4 + 1] + bih[gbase + 1] + bhh[gbase + 1];
                o.z = acc[i][jj * 4 + 2] + bih[gbase + 2] + bhh[gbase + 2];
                o.w = acc[i][jj * 4 + 3] + bih[gbase + 3] + bhh[gbase + 3];
                *(float4*)&orow[gbase] = o;
            } else {
                for (int e = 0; e < 4; ++e) {
                    int g = gbase + e;
                    if (g < 600) orow[g] = acc[i][jj * 4 + e] + bih[g] + bhh[g];
                }
            }
        }
    }
}

// ---------------- encoder dir1 gates at t=127 only ----------------
__global__ void k_encgx1(const float* __restrict__ hs0, const float* __restrict__ hs1,
                         const float* __restrict__ hs2, const float* __restrict__ wih,
                         const float* __restrict__ bih, const float* __restrict__ bhh,
                         float* __restrict__ gx1) {
    __shared__ __align__(16) float sh[192];
    int b = blockIdx.x, tid = threadIdx.x;
    if (tid < 192) {
        const float* src = (tid < 64 ? hs0 : (tid < 128 ? hs1 : hs2));
        sh[tid] = src[b * 8192 + 127 * 64 + (tid & 63)];
    }
    __syncthreads();
    const float* w1 = wih + 600 * 192;
    for (int g = tid; g < 600; g += 256) {
        float acc = bih[600 + g] + bhh[600 + g];
        const float4* wr = (const float4*)(w1 + g * 192);
        #pragma unroll 8
        for (int q = 0; q < 48; ++q) {
            float4 wv = wr[q];
            float4 hv = *(const float4*)&sh[q * 4];
            acc = fmaf(wv.x, hv.x, acc);
            acc = fmaf(wv.y, hv.y, acc);
            acc = fmaf(wv.z, hv.z, acc);
            acc = fmaf(wv.w, hv.w, acc);
        }
        gx1[b * 600 + g] = acc;
    }
}

// ---------------- prefix sums of dec_wih rows: PT[k][dg], k=0..300 ----------------
__global__ void k_ptpref(const float* __restrict__ dwih, float* __restrict__ PT) {
    int dg = blockIdx.x * 256 + threadIdx.x;
    if (dg >= 1200) return;
    const float* wr = dwih + dg * 300;
    float run = 0.f;
    PT[dg] = 0.f;
    for (int k = 0; k < 300; ++k) {
        run += wr[k];
        PT[(k + 1) * 1200 + dg] = run;
    }
}

// ---------------- PD[(dirt*600+g)*4 + seg] ----------------
__global__ void k_pd(const float* __restrict__ PT, float* __restrict__ PD) {
    int id = blockIdx.x * 256 + threadIdx.x;
    if (id >= 153600) return;                 // 2*128*600
    int g = id % 600;
    int tt = id / 600;
    int t = tt & 127, dir = tt >> 7;
    int dg = dir * 600 + g;
    int base = t * 300;
    int j0 = base >> 7;
    int ke1 = (j0 + 1) * 128 - base;
    int ke2 = ke1 + 128; ke2 = ke2 > 300 ? 300 : ke2;
    int ke3 = ke1 + 256; ke3 = ke3 > 300 ? 300 : ke3;
    float p1 = PT[ke1 * 1200 + dg];
    float p2 = PT[ke2 * 1200 + dg];
    float p3 = PT[ke3 * 1200 + dg];
    float p4 = PT[300 * 1200 + dg];
    float4 o = {p1, p2 - p1, p3 - p2, p4 - p3};
    *(float4*)&PD[id * 4] = o;
}

// ---------------- encoder LSTM (R4 layout): thread = gate row; lane quad = hidden unit ----------------
__global__ __launch_bounds__(640, 3) void k_enclstm(
    const float* __restrict__ gx0, const float* __restrict__ gx1,
    const float* __restrict__ whh, float* __restrict__ h_end) {
    int bid = blockIdx.x, t = threadIdx.x;
    if (bid >= 128) {  // one bwd step from zero state on x_{127}
        int b = bid - 128;
        if (t < 150) {
            float ai = gx1[b * 600 + t];
            float ag = gx1[b * 600 + 300 + t];
            float ao = gx1[b * 600 + 450 + t];
            float c = sigm(ai) * tanhfast(ag);
            h_end[b * 300 + 150 + t] = sigm(ao) * tanhfast(c);
        }
        return;
    }
    __shared__ __align__(16) _Float16 hbuf[2][152];
    int b = bid;
    bool on = t < 600;
    int j = t >> 2, g4 = t & 3;
    int grow = g4 * 150 + j;          // raw gate row (i,f,g,o blocks of 150)
    v2h wv[76];
    #pragma unroll
    for (int p = 0; p < 76; ++p) wv[p] = pk2(0.f, 0.f);
    if (on) {
        const float* r = whh + grow * 150;
        #pragma unroll
        for (int p = 0; p < 75; ++p) wv[p] = pk2(r[2 * p], r[2 * p + 1]);
    }
    for (int i = t; i < 304; i += 640) ((_Float16*)hbuf)[i] = (_Float16)0.f;
    float c = 0.f;
    float xc = on ? gx0[(b * 128) * 600 + grow] : 0.f;
    barrier_lds();
    for (int s = 0; s < 128; ++s) {
        float xn = (on && s < 127) ? gx0[(b * 128 + s + 1) * 600 + grow] : 0.f;
        float s0 = 0.f, s1 = 0.f, s2 = 0.f, s3 = 0.f;
        const float4* hp = (const float4*)hbuf[s & 1];
        #pragma unroll
        for (int cc = 0; cc < 19; ++cc) {
            float4 hv = hp[cc];
            s0 = fdot2(wv[4 * cc + 0], __builtin_bit_cast(v2h, hv.x), s0);
            s1 = fdot2(wv[4 * cc + 1], __builtin_bit_cast(v2h, hv.y), s1);
            s2 = fdot2(wv[4 * cc + 2], __builtin_bit_cast(v2h, hv.z), s2);
            s3 = fdot2(wv[4 * cc + 3], __builtin_bit_cast(v2h, hv.w), s3);
        }
        float a = xc + ((s0 + s1) + (s2 + s3));
        bool isg = (g4 == 2);
        float sg = sigm(isg ? 2.f * a : a);
        float act = isg ? fmaf(2.f, sg, -1.f) : sg;   // tanh(x)=2*sigm(2x)-1
        float vf = __shfl_xor(act, 1);
        float vg = __shfl_xor(act, 2);
        float vo = __shfl_xor(vf, 2);
        if (on && g4 == 0) {
            c = fmaf(vf, c, act * vg);                // c = sigm(f)*c + sigm(i)*tanh(g)
            float h = vo * tanhfast(c);               // h = sigm(o)*tanh(c)
            hbuf[(s + 1) & 1][j] = (_Float16)h;
            if (s == 127) h_end[b * 300 + j] = h;
        }
        xc = xn;
        barrier_lds();
    }
}

// ---------------- decoder LSTM (R4 layout, both dirs), x-part via PD; fp16 dec out ----------------
__global__ __launch_bounds__(640, 3) void k_declstm(
    const float* __restrict__ PD, const float* __restrict__ hend,
    const float* __restrict__ whh_all, const float* __restrict__ bih,
    const float* __restrict__ bhh, _Float16* __restrict__ dec_out) {
    __shared__ __align__(16) float she[304];
    __shared__ __align__(16) _Float16 hbuf[2][152];
    int dir = blockIdx.x >> 7, b = blockIdx.x & 127;
    int t = threadIdx.x;
    bool on = t < 600;
    int j = t >> 2, g4 = t & 3;
    int grow = g4 * 150 + j;
    v2h wv[76];
    #pragma unroll
    for (int p = 0; p < 76; ++p) wv[p] = pk2(0.f, 0.f);
    float bias = 0.f;
    if (on) {
        const float* r = whh_all + dir * 90000 + grow * 150;
        #pragma unroll
        for (int p = 0; p < 75; ++p) wv[p] = pk2(r[2 * p], r[2 * p + 1]);
        bias = bih[dir * 600 + grow] + bhh[dir * 600 + grow];
    }
    for (int i = t; i < 304; i += 640) she[i] = (i < 300) ? hend[b * 300 + i] : 0.f;
    for (int i = t; i < 304; i += 640) ((_Float16*)hbuf)[i] = (_Float16)0.f;
    float c = 0.f;
    int t0 = dir ? 127 : 0;
    float4 pd = {0.f, 0.f, 0.f, 0.f};
    if (on) pd = *(const float4*)&PD[((dir * 128 + t0) * 600 + grow) * 4];
    barrier_lds();
    for (int s = 0; s < 128; ++s) {
        int tt = dir ? (127 - s) : s;
        float4 pdn = {0.f, 0.f, 0.f, 0.f};
        if (on && s < 127) {
            int tn = dir ? (126 - s) : (s + 1);
            pdn = *(const float4*)&PD[((dir * 128 + tn) * 600 + grow) * 4];
        }
        int j0 = (tt * 300) >> 7;
        float e0 = she[j0], e1 = she[j0 + 1], e2 = she[j0 + 2], e3 = she[j0 + 3];
        float a = bias + e0 * pd.x + e1 * pd.y + e2 * pd.z + e3 * pd.w;
        float s0 = 0.f, s1 = 0.f, s2 = 0.f, s3 = 0.f;
        const float4* hp = (const float4*)hbuf[s & 1];
        #pragma unroll
        for (int cc = 0; cc < 19; ++cc) {
            float4 hv = hp[cc];
            s0 = fdot2(wv[4 * cc + 0], __builtin_bit_cast(v2h, hv.x), s0);
            s1 = fdot2(wv[4 * cc + 1], __builtin_bit_cast(v2h, hv.y), s1);
            s2 = fdot2(wv[4 * cc + 2], __builtin_bit_cast(v2h, hv.z), s2);
            s3 = fdot2(wv[4 * cc + 3], __builtin_bit_cast(v2h, hv.w), s3);
        }
        a += (s0 + s1) + (s2 + s3);
        bool isg = (g4 == 2);
        float sg = sigm(isg ? 2.f * a : a);
        float act = isg ? fmaf(2.f, sg, -1.f) : sg;
        float vf = __shfl_xor(act, 1);
        float vg = __shfl_xor(act, 2);
        float vo = __shfl_xor(vf, 2);
        if (on && g4 == 0) {
            c = fmaf(vf, c, act * vg);
            float h = vo * tanhfast(c);
            hbuf[(s + 1) & 1][j] = (_Float16)h;
            dec_out[(b * 128 + tt) * 300 + dir * 150 + j] = (_Float16)h;
        }
        pd = pdn;
        barrier_lds();
    }
}

// ---------------- final: out = dec(fp16) @ fc_w^T + fc_b, fp16 dot2 ----------------
__global__ __launch_bounds__(256) void k_fingemm(const _Float16* __restrict__ decH,
                                                 const float* __restrict__ fw,
                                                 const float* __restrict__ fb,
                                                 float* __restrict__ out) {
    __shared__ __align__(16) unsigned AsT[16 * 68];  // [kk2][m] v2h
    __shared__ __align__(16) unsigned FwT[16 * 68];  // [kk2][n] v2h
    int r0 = blockIdx.x * 64, tid = threadIdx.x;
    int ty = tid >> 4, tx = tid & 15;
    float acc[4][4];
    #pragma unroll
    for (int r = 0; r < 4; ++r)
        #pragma unroll
        for (int c = 0; c < 4; ++c) acc[r][c] = 0.f;
    for (int kc = 0; kc < 10; ++kc) {
        int k0 = kc * 32;
        for (int f = tid; f < 1024; f += 256) {
            int m = f >> 4, kk2 = f & 15;
            int k = k0 + kk2 * 2;
            AsT[kk2 * 68 + m] =
                (k + 1 < 300) ? *(const unsigned*)&decH[(r0 + m) * 300 + k] : 0u;
        }
        for (int f = tid; f < 1024; f += 256) {
            int n = f >> 4, kk2 = f & 15;
            int k = k0 + kk2 * 2;
            FwT[kk2 * 68 + n] =
                (k + 1 < 300) ? pku(fw[n * 300 + k], fw[n * 300 + k + 1]) : 0u;
        }
        __syncthreads();
        #pragma unroll 4
        for (int kk2 = 0; kk2 < 16; ++kk2) {
            uint4 a4 = *(const uint4*)&AsT[kk2 * 68 + ty * 4];
            uint4 w4 = *(const uint4*)&FwT[kk2 * 68 + tx * 4];
            v2h a0 = upk(a4.x), a1 = upk(a4.y), a2 = upk(a4.z), a3 = upk(a4.w);
            v2h w0 = upk(w4.x), w1 = upk(w4.y), w2 = upk(w4.z), w3 = upk(w4.w);
            acc[0][0] = fdot2(a0, w0, acc[0][0]); acc[0][1] = fdot2(a0, w1, acc[0][1]);
            acc[0][2] = fdot2(a0, w2, acc[0][2]); acc[0][3] = fdot2(a0, w3, acc[0][3]);
            acc[1][0] = fdot2(a1, w0, acc[1][0]); acc[1][1] = fdot2(a1, w1, acc[1][1]);
            acc[1][2] = fdot2(a1, w2, acc[1][2]); acc[1][3] = fdot2(a1, w3, acc[1][3]);
            acc[2][0] = fdot2(a2, w0, acc[2][0]); acc[2][1] = fdot2(a2, w1, acc[2][1]);
            acc[2][2] = fdot2(a2, w2, acc[2][2]); acc[2][3] = fdot2(a2, w3, acc[2][3]);
            acc[3][0] = fdot2(a3, w0, acc[3][0]); acc[3][1] = fdot2(a3, w1, acc[3][1]);
            acc[3][2] = fdot2(a3, w2, acc[3][2]); acc[3][3] = fdot2(a3, w3, acc[3][3]);
        }
        __syncthreads();
    }
    for (int r = 0; r < 4; ++r) {
        int m = r0 + ty * 4 + r;
        float4 o4;
        o4.x = acc[r][0] + fb[tx * 4 + 0];
        o4.y = acc[r][1] + fb[tx * 4 + 1];
        o4.z = acc[r][2] + fb[tx * 4 + 2];
        o4.w = acc[r][3] + fb[tx * 4 + 3];
        *(float4*)&out[m * 64 + tx * 4] = o4;
    }
}

// ---------------- host launcher ----------------
extern "C" void kernel_launch(void* const* d_in, const int* in_sizes, int n_in,
                              void* d_out, int out_size, void* d_ws, size_t ws_size,
                              hipStream_t stream) {
    const float* x = (const float*)d_in[0];
    const float* c2w = (const float*)d_in[3];
    const float* c2b = (const float*)d_in[4];
    const float* c3w = (const float*)d_in[5];
    const float* c3b = (const float*)d_in[6];
    const float* gatw = (const float*)d_in[7];
    const float* gatas = (const float*)d_in[8];
    const float* gatad = (const float*)d_in[9];
    const float* gatb = (const float*)d_in[10];
    const float* gcnw = (const float*)d_in[11];
    const float* gcnb = (const float*)d_in[12];
    const float* lwih = (const float*)d_in[13];
    const float* lwhh = (const float*)d_in[14];
    const float* lbih = (const float*)d_in[15];
    const float* lbhh = (const float*)d_in[16];
    const float* dwih = (const float*)d_in[17];
    const float* dwhh = (const float*)d_in[18];
    const float* dbih = (const float*)d_in[19];
    const float* dbhh = (const float*)d_in[20];
    const float* fcw = (const float*)d_in[21];
    const float* fcb = (const float*)d_in[22];
    float* out = (float*)d_out;
    float* ws = (float*)d_ws;

    float* hs0 = ws;                    // 1,048,576
    float* hs1 = ws + 1048576;          // 1,048,576
    float* hs2 = ws + 2097152;          // 1,048,576
    float* gx0 = ws + 3145728;          // 9,830,400
    float* gx1 = ws + 12976128;         // 76,800
    float* hend = ws + 13052928;        // 38,400
    float* PT = ws + 13091328;          // 361,200
    _Float16* decH = (_Float16*)(ws + 13452528);  // 4,915,200 halfs (fits old dec region)
    float* PD = hs0;                    // 614,400 — overlays hs0 (dead after encgemm/encgx1)

    k_copy<<<1024, 256, 0, stream>>>(x, hs0);
    k_conv2<<<dim3(128, 2, 2), 256, (70 * 68 + 7 * 16 * 256) * 4, stream>>>(
        x, c2w, c2b, c3w, c3b, hs1, hs2);
    for (int l = 0; l < 2; ++l)
        k_stgat<<<dim3(128, 3), 256, 77824, stream>>>(hs0, hs1, hs2, gatw, gatas,
                                                      gatad, gatb, gcnw, gcnb, l);
    k_encgemm2<<<dim3(128, 5), 256, 0, stream>>>(hs0, hs1, hs2, lwih, lbih, lbhh, gx0);
    k_encgx1<<<128, 256, 0, stream>>>(hs0, hs1, hs2, lwih, lbih, lbhh, gx1);
    k_ptpref<<<5, 256, 0, stream>>>(dwih, PT);
    k_pd<<<600, 256, 0, stream>>>(PT, PD);   // after encgemm/encgx1: hs0 region now dead
    k_enclstm<<<256, 640, 0, stream>>>(gx0, gx1, lwhh, hend);
    k_declstm<<<256, 640, 0, stream>>>(PD, hend, dwhh, dbih, dbhh, decH);
    k_fingemm<<<256, 256, 0, stream>>>(decH, fcw, fcb, out);
}

// Round 14
// 521.276 us; speedup vs baseline: 2.0093x; 1.0417x over previous
//
#include <hip/hip_runtime.h>
#include <hip/hip_fp16.h>

// ---------------- model dims ----------------
// B=128, W=128, N=64, HID=150, L=2
// gates = 4*HID = 600 ; enc input D = 3*N = 192 ; dec input = 2*HID = 300
//
// LSTM design note (R5-R12): the 640-thread quad-gate scan layout (76 weight
// VGPRs/thread, VGPR_Count=84) is the proven optimum on this toolchain. The
// compiler hard-caps VGPR allocation at 128 (4-wave scheduler target) and
// silently spills past it — launch_bounds min-waves, amdgpu_waves_per_eu,
// and macro-ized array access all fail to unlock more. MFMA-batched LSTM
// (R11/R12) is latency-bound at 1-2% occupancy: B-frags can't stay register-
// resident (>128 cap) nor LDS-resident (200KB/block), and a 1-stage prefetch
// ring covers <20% of the L2 latency. Do not revisit without a new compiler.

typedef _Float16 v2h __attribute__((ext_vector_type(2)));

__device__ __forceinline__ float sigm(float x) {
    return 1.0f / (1.0f + __expf(-x));
}
__device__ __forceinline__ float tanhfast(float x) {
    return 2.0f / (1.0f + __expf(-2.0f * x)) - 1.0f;
}
__device__ __forceinline__ v2h pk2(float a, float b) {
    v2h r; r[0] = (_Float16)a; r[1] = (_Float16)b; return r;
}
__device__ __forceinline__ unsigned pku(float a, float b) {
    return __builtin_bit_cast(unsigned, pk2(a, b));
}
__device__ __forceinline__ v2h upk(unsigned u) { return __builtin_bit_cast(v2h, u); }
__device__ __forceinline__ float fdot2(v2h a, v2h b, float c) {
#if __has_builtin(__builtin_amdgcn_fdot2)
    return __builtin_amdgcn_fdot2(a, b, c, false);
#else
    return c + (float)a[0] * (float)b[0] + (float)a[1] * (float)b[1];
#endif
}

// LDS-only workgroup barrier (orders ds ops; leaves global loads in flight).
__device__ __forceinline__ void barrier_lds() {
    asm volatile("s_waitcnt lgkmcnt(0)" ::: "memory");
    __builtin_amdgcn_s_barrier();
}

// ---------------- conv branches (merged) ----------------
__global__ __launch_bounds__(256) void k_conv2(
    const float* __restrict__ x,
    const float* __restrict__ cw5, const float* __restrict__ cb5,
    const float* __restrict__ cw7, const float* __restrict__ cb7,
    float* __restrict__ hs1, float* __restrict__ hs2) {
    extern __shared__ float S[];
    float* xt = S;              // [70][68]
    float* wl = S + 70 * 68;    // [(t*16+i4)*256 + o*4 + j]
    int b = blockIdx.x, wh = blockIdx.y, br = blockIdx.z;
    int K = br ? 7 : 5;
    const float* cw = br ? cw7 : cw5;
    const float* cb = br ? cb7 : cb5;
    float* dst = br ? hs2 : hs1;
    int w0 = wh * 64;
    int tid = threadIdx.x;

    for (int f = tid; f < 70 * 64; f += 256) {
        int ww = f >> 6, i = f & 63;
        int wp = w0 - 3 + ww;
        xt[ww * 68 + i] = ((unsigned)wp < 128u) ? x[b * 8192 + wp * 64 + i] : 0.f;
    }
    int nw = K * 4096;
    for (int f = tid; f < nw; f += 256) {
        int j = f & 3, o = (f >> 2) & 63, i4 = (f >> 8) & 15, t = f >> 12;
        wl[f] = cw[(o * 64 + i4 * 4 + j) * K + t];
    }
    __syncthreads();

    int to = tid & 15, tw = tid >> 4;
    float acc[4][4] = {};
    int ob = 3 - (K >> 1);
    for (int t = 0; t < K; ++t) {
        int rbase = tw * 4 + t + ob;
        for (int i4 = 0; i4 < 16; ++i4) {
            float4 a0 = *(const float4*)&xt[(rbase + 0) * 68 + i4 * 4];
            float4 a1 = *(const float4*)&xt[(rbase + 1) * 68 + i4 * 4];
            float4 a2 = *(const float4*)&xt[(rbase + 2) * 68 + i4 * 4];
            float4 a3 = *(const float4*)&xt[(rbase + 3) * 68 + i4 * 4];
            const float* wrow = &wl[(t * 16 + i4) * 256];
            float4 b0 = *(const float4*)&wrow[to * 4];
            float4 b1 = *(const float4*)&wrow[(to + 16) * 4];
            float4 b2 = *(const float4*)&wrow[(to + 32) * 4];
            float4 b3 = *(const float4*)&wrow[(to + 48) * 4];
            #define DOT4(w_, a_) \
                acc[w_][0] = fmaf(a_.x, b0.x, acc[w_][0]); acc[w_][0] = fmaf(a_.y, b0.y, acc[w_][0]); \
                acc[w_][0] = fmaf(a_.z, b0.z, acc[w_][0]); acc[w_][0] = fmaf(a_.w, b0.w, acc[w_][0]); \
                acc[w_][1] = fmaf(a_.x, b1.x, acc[w_][1]); acc[w_][1] = fmaf(a_.y, b1.y, acc[w_][1]); \
                acc[w_][1] = fmaf(a_.z, b1.z, acc[w_][1]); acc[w_][1] = fmaf(a_.w, b1.w, acc[w_][1]); \
                acc[w_][2] = fmaf(a_.x, b2.x, acc[w_][2]); acc[w_][2] = fmaf(a_.y, b2.y, acc[w_][2]); \
                acc[w_][2] = fmaf(a_.z, b2.z, acc[w_][2]); acc[w_][2] = fmaf(a_.w, b2.w, acc[w_][2]); \
                acc[w_][3] = fmaf(a_.x, b3.x, acc[w_][3]); acc[w_][3] = fmaf(a_.y, b3.y, acc[w_][3]); \
                acc[w_][3] = fmaf(a_.z, b3.z, acc[w_][3]); acc[w_][3] = fmaf(a_.w, b3.w, acc[w_][3]);
            DOT4(0, a0)
            DOT4(1, a1)
            DOT4(2, a2)
            DOT4(3, a3)
            #undef DOT4
        }
    }
    #pragma unroll
    for (int wj = 0; wj < 4; ++wj) {
        int w = w0 + tw * 4 + wj;
        #pragma unroll
        for (int oj = 0; oj < 4; ++oj) {
            int o = to + 16 * oj;
            dst[b * 8192 + w * 64 + o] = fmaxf(acc[wj][oj] + cb[o], 0.f);
        }
    }
}

// ---------------- one STGAT layer (all 3 branches), fp16 dot2 ----------------
// grid (128 b, 3 br), block 256, dyn LDS 77824 B -> 2 blocks/CU
// Reads from `src` (= x for l==0,br==0 — removes the k_copy kernel), writes hs.
__global__ __launch_bounds__(256, 2) void k_stgat(
    const float* __restrict__ xin,
    float* __restrict__ hs0, float* __restrict__ hs1, float* __restrict__ hs2,
    const float* __restrict__ gat_w, const float* __restrict__ gat_asrc,
    const float* __restrict__ gat_adst, const float* __restrict__ gat_b,
    const float* __restrict__ gcn_w, const float* __restrict__ gcn_b, int l) {
    extern __shared__ float S[];
    _Float16* Sh = (_Float16*)S;
    const int XHh = 0;           // xp fp16 [64 n][132 w]
    const int GHh = 8448;        // gw fp16 [128 wo][132 k]
    const int HHTh = 25344;      // h^T fp16 [128 wo][68 n]
    const int AHh = 34560;       // A fp16 [64 j][68 i]
    const int FHh = 8448;        // f^T fp16 [128 w][68 n]
    const int CHh = 0;           // cw fp16 [64 c][68 k]
    const int SDo = 17024;       // s[64], d[64]
    const int CSo = 17024;       // chunk sums [4][64]
    const int HGo = 8576;        // hg fp32 [128 w][66 c]

    int b = blockIdx.x, br = blockIdx.y, tid = threadIdx.x;
    float* hs = (br == 0 ? hs0 : (br == 1 ? hs1 : hs2)) + b * 8192;
    const float* src = (l == 0 && br == 0) ? (xin + b * 8192) : hs;
    int wsel = br * 2 + l;
    const float* gw = gat_w + wsel * 16384;
    const float* asr = gat_asrc + wsel * 128;
    const float* ads = gat_adst + wsel * 128;
    const float* gb = gat_b + wsel * 128;
    const float* cwp = gcn_w + wsel * 4096;
    const float* cbp = gcn_b + wsel * 64;

    {
        const float4* hsv = (const float4*)src;
        for (int mt = tid; mt < 512; mt += 256) {
            int ng = mt & 15, wg = mt >> 4;
            float4 r0 = hsv[(wg * 4 + 0) * 16 + ng];
            float4 r1 = hsv[(wg * 4 + 1) * 16 + ng];
            float4 r2 = hsv[(wg * 4 + 2) * 16 + ng];
            float4 r3 = hsv[(wg * 4 + 3) * 16 + ng];
            int n0 = ng * 4, ww = wg * 4;
            *(uint2*)&Sh[XHh + (n0 + 0) * 132 + ww] = make_uint2(pku(r0.x, r1.x), pku(r2.x, r3.x));
            *(uint2*)&Sh[XHh + (n0 + 1) * 132 + ww] = make_uint2(pku(r0.y, r1.y), pku(r2.y, r3.y));
            *(uint2*)&Sh[XHh + (n0 + 2) * 132 + ww] = make_uint2(pku(r0.z, r1.z), pku(r2.z, r3.z));
            *(uint2*)&Sh[XHh + (n0 + 3) * 132 + ww] = make_uint2(pku(r0.w, r1.w), pku(r2.w, r3.w));
        }
        const float4* gwv = (const float4*)gw;
        for (int f4 = tid; f4 < 4096; f4 += 256) {
            float4 v = gwv[f4];
            int wo = f4 >> 5, k4 = f4 & 31;
            *(uint2*)&Sh[GHh + wo * 132 + k4 * 4] = make_uint2(pku(v.x, v.y), pku(v.z, v.w));
        }
    }
    __syncthreads();

    int wq = tid & 15, nq = tid >> 4;
    {
        float asv[8], adv[8];
        #pragma unroll
        for (int c = 0; c < 8; ++c) { asv[c] = asr[wq + 16 * c]; adv[c] = ads[wq + 16 * c]; }
        float acc0[8] = {}, acc1[8] = {}, acc2[8] = {}, acc3[8] = {};
        const _Float16* Arow = Sh + XHh + nq * 4 * 132;
        const _Float16* Brow = Sh + GHh + wq * 132;
        for (int k4 = 0; k4 < 32; ++k4) {
            uint2 u0 = *(const uint2*)&Arow[k4 * 4];
            uint2 u1 = *(const uint2*)&Arow[132 + k4 * 4];
            uint2 u2 = *(const uint2*)&Arow[264 + k4 * 4];
            uint2 u3 = *(const uint2*)&Arow[396 + k4 * 4];
            v2h a0l = upk(u0.x), a0h = upk(u0.y), a1l = upk(u1.x), a1h = upk(u1.y);
            v2h a2l = upk(u2.x), a2h = upk(u2.y), a3l = upk(u3.x), a3h = upk(u3.y);
            #pragma unroll
            for (int c = 0; c < 8; ++c) {
                uint2 ub = *(const uint2*)&Brow[c * (16 * 132) + k4 * 4];
                v2h bl = upk(ub.x), bh = upk(ub.y);
                acc0[c] = fdot2(a0l, bl, acc0[c]); acc0[c] = fdot2(a0h, bh, acc0[c]);
                acc1[c] = fdot2(a1l, bl, acc1[c]); acc1[c] = fdot2(a1h, bh, acc1[c]);
                acc2[c] = fdot2(a2l, bl, acc2[c]); acc2[c] = fdot2(a2h, bh, acc2[c]);
                acc3[c] = fdot2(a3l, bl, acc3[c]); acc3[c] = fdot2(a3h, bh, acc3[c]);
            }
        }
        #pragma unroll
        for (int c = 0; c < 8; ++c)
            *(uint2*)&Sh[HHTh + (wq + 16 * c) * 68 + nq * 4] =
                make_uint2(pku(acc0[c], acc1[c]), pku(acc2[c], acc3[c]));
        float ps0 = 0, ps1 = 0, ps2 = 0, ps3 = 0, pd0 = 0, pd1 = 0, pd2 = 0, pd3 = 0;
        #pragma unroll
        for (int c = 0; c < 8; ++c) {
            ps0 = fmaf(acc0[c], asv[c], ps0); ps1 = fmaf(acc1[c], asv[c], ps1);
            ps2 = fmaf(acc2[c], asv[c], ps2); ps3 = fmaf(acc3[c], asv[c], ps3);
            pd0 = fmaf(acc0[c], adv[c], pd0); pd1 = fmaf(acc1[c], adv[c], pd1);
            pd2 = fmaf(acc2[c], adv[c], pd2); pd3 = fmaf(acc3[c], adv[c], pd3);
        }
        #pragma unroll
        for (int m = 1; m < 16; m <<= 1) {
            ps0 += __shfl_xor(ps0, m); ps1 += __shfl_xor(ps1, m);
            ps2 += __shfl_xor(ps2, m); ps3 += __shfl_xor(ps3, m);
            pd0 += __shfl_xor(pd0, m); pd1 += __shfl_xor(pd1, m);
            pd2 += __shfl_xor(pd2, m); pd3 += __shfl_xor(pd3, m);
        }
        if (wq == 0) {
            S[SDo + nq * 4 + 0] = ps0; S[SDo + nq * 4 + 1] = ps1;
            S[SDo + nq * 4 + 2] = ps2; S[SDo + nq * 4 + 3] = ps3;
            S[SDo + 64 + nq * 4 + 0] = pd0; S[SDo + 64 + nq * 4 + 1] = pd1;
            S[SDo + 64 + nq * 4 + 2] = pd2; S[SDo + 64 + nq * 4 + 3] = pd3;
        }
    }
    __syncthreads();

    {
        const float4* cwv = (const float4*)cwp;
        for (int f4 = tid; f4 < 1024; f4 += 256) {
            float4 v = cwv[f4];
            int c = f4 >> 4, k4 = f4 & 15;
            *(uint2*)&Sh[CHh + c * 68 + k4 * 4] = make_uint2(pku(v.x, v.y), pku(v.z, v.w));
        }
        if (tid < 64) {
            int j = tid;
            float dj = S[SDo + 64 + j];
            float mx = -1e30f;
            for (int i = 0; i < 64; ++i) {
                float e = S[SDo + i] + dj;
                e = (e > 0.f) ? e : 0.2f * e;
                mx = fmaxf(mx, e);
            }
            float sum = 0.f;
            for (int i = 0; i < 64; i += 2) {
                float e0 = S[SDo + i] + dj;     e0 = (e0 > 0.f) ? e0 : 0.2f * e0;
                float e1 = S[SDo + i + 1] + dj; e1 = (e1 > 0.f) ? e1 : 0.2f * e1;
                float x0 = __expf(e0 - mx), x1 = __expf(e1 - mx);
                sum += x0 + x1;
                *(unsigned*)&Sh[AHh + j * 68 + i] = pku(x0, x1);
            }
            float rinv = 1.f / sum;
            for (int i = 0; i < 64; i += 2) {
                v2h v = upk(*(const unsigned*)&Sh[AHh + j * 68 + i]);
                *(unsigned*)&Sh[AHh + j * 68 + i] = pku((float)v[0] * rinv, (float)v[1] * rinv);
            }
        }
    }
    __syncthreads();

    {
        float gbv[8];
        #pragma unroll
        for (int c = 0; c < 8; ++c) gbv[c] = gb[wq + 16 * c];
        float acc0[8] = {}, acc1[8] = {}, acc2[8] = {}, acc3[8] = {};
        const _Float16* Arow = Sh + AHh + nq * 4 * 68;
        const _Float16* Brow = Sh + HHTh + wq * 68;
        for (int k4 = 0; k4 < 16; ++k4) {
            uint2 u0 = *(const uint2*)&Arow[k4 * 4];
            uint2 u1 = *(const uint2*)&Arow[68 + k4 * 4];
            uint2 u2 = *(const uint2*)&Arow[136 + k4 * 4];
            uint2 u3 = *(const uint2*)&Arow[204 + k4 * 4];
            v2h a0l = upk(u0.x), a0h = upk(u0.y), a1l = upk(u1.x), a1h = upk(u1.y);
            v2h a2l = upk(u2.x), a2h = upk(u2.y), a3l = upk(u3.x), a3h = upk(u3.y);
            #pragma unroll
            for (int c = 0; c < 8; ++c) {
                uint2 ub = *(const uint2*)&Brow[c * (16 * 68) + k4 * 4];
                v2h bl = upk(ub.x), bh = upk(ub.y);
                acc0[c] = fdot2(a0l, bl, acc0[c]); acc0[c] = fdot2(a0h, bh, acc0[c]);
                acc1[c] = fdot2(a1l, bl, acc1[c]); acc1[c] = fdot2(a1h, bh, acc1[c]);
                acc2[c] = fdot2(a2l, bl, acc2[c]); acc2[c] = fdot2(a2h, bh, acc2[c]);
                acc3[c] = fdot2(a3l, bl, acc3[c]); acc3[c] = fdot2(a3h, bh, acc3[c]);
            }
        }
        #pragma unroll
        for (int c = 0; c < 8; ++c) {
            float f0 = fmaxf(acc0[c] + gbv[c], 0.f);
            float f1 = fmaxf(acc1[c] + gbv[c], 0.f);
            float f2 = fmaxf(acc2[c] + gbv[c], 0.f);
            float f3 = fmaxf(acc3[c] + gbv[c], 0.f);
            *(uint2*)&Sh[FHh + (wq + 16 * c) * 68 + nq * 4] = make_uint2(pku(f0, f1), pku(f2, f3));
        }
    }
    __syncthreads();

    {
        int cq = tid & 7, wg = tid >> 3;
        float acc0[8] = {}, acc1[8] = {}, acc2[8] = {}, acc3[8] = {};
        const _Float16* Arow = Sh + FHh + wg * 4 * 68;
        const _Float16* Brow = Sh + CHh + cq * 68;
        for (int k4 = 0; k4 < 16; ++k4) {
            uint2 u0 = *(const uint2*)&Arow[k4 * 4];
            uint2 u1 = *(const uint2*)&Arow[68 + k4 * 4];
            uint2 u2 = *(const uint2*)&Arow[136 + k4 * 4];
            uint2 u3 = *(const uint2*)&Arow[204 + k4 * 4];
            v2h a0l = upk(u0.x), a0h = upk(u0.y), a1l = upk(u1.x), a1h = upk(u1.y);
            v2h a2l = upk(u2.x), a2h = upk(u2.y), a3l = upk(u3.x), a3h = upk(u3.y);
            #pragma unroll
            for (int cc = 0; cc < 8; ++cc) {
                uint2 ub = *(const uint2*)&Brow[cc * (8 * 68) + k4 * 4];
                v2h bl = upk(ub.x), bh = upk(ub.y);
                acc0[cc] = fdot2(a0l, bl, acc0[cc]); acc0[cc] = fdot2(a0h, bh, acc0[cc]);
                acc1[cc] = fdot2(a1l, bl, acc1[cc]); acc1[cc] = fdot2(a1h, bh, acc1[cc]);
                acc2[cc] = fdot2(a2l, bl, acc2[cc]); acc2[cc] = fdot2(a2h, bh, acc2[cc]);
                acc3[cc] = fdot2(a3l, bl, acc3[cc]); acc3[cc] = fdot2(a3h, bh, acc3[cc]);
            }
        }
        #pragma unroll
        for (int cc = 0; cc < 8; ++cc) {
            int c = cq + 8 * cc;
            S[HGo + (wg * 4 + 0) * 66 + c] = acc0[cc];
            S[HGo + (wg * 4 + 1) * 66 + c] = acc1[cc];
            S[HGo + (wg * 4 + 2) * 66 + c] = acc2[cc];
            S[HGo + (wg * 4 + 3) * 66 + c] = acc3[cc];
        }
    }
    __syncthreads();

    {
        int c = tid & 63, q = tid >> 6;
        float local = 0.f;
        for (int i = 0; i < 32; ++i) {
            int w = q * 32 + i;
            local = fmaf(rsqrtf((float)(w + 1)), S[HGo + w * 66 + c], local);
        }
        S[CSo + q * 64 + c] = local;
    }
    __syncthreads();
    {
        int c = tid & 63, q = tid >> 6;
        float run = 0.f;
        for (int qq = 0; qq < q; ++qq) run += S[CSo + qq * 64 + c];
        float cbv = cbp[c];
        for (int i = 0; i < 32; ++i) {
            int w = q * 32 + i;
            float dv = rsqrtf((float)(w + 1));
            run = fmaf(dv, S[HGo + w * 66 + c], run);
            S[HGo + w * 66 + c] = fmaxf(fmaf(dv, run, cbv), 0.f);
        }
    }
    __syncthreads();

    {
        const float4* srcv4 = (const float4*)src;
        float4* dstv4 = (float4*)hs;
        for (int f4 = tid; f4 < 2048; f4 += 256) {
            int a = f4 >> 4, cc0 = (f4 & 15) * 4;
            float4 old = srcv4[f4];
            int n = a & 63, ahi = a >> 6;
            old.x += S[HGo + (cc0 * 2 + ahi) * 66 + n];
            old.y += S[HGo + ((cc0 + 1) * 2 + ahi) * 66 + n];
            old.z += S[HGo + ((cc0 + 2) * 2 + ahi) * 66 + n];
            old.w += S[HGo + ((cc0 + 3) * 2 + ahi) * 66 + n];
            dstv4[f4] = old;
        }
    }
}

// ---------------- encoder input GEMM (dir0 full) + fused dir1 t=127 gates ----------------
// grid (128 b, 6 gy), block 256. gy<5: fp16 dot2 GEMM tile; gy==5: gx1 path.
__global__ __launch_bounds__(256) void k_encgemm2(
    const float* __restrict__ hs0, const float* __restrict__ hs1, const float* __restrict__ hs2,
    const float* __restrict__ wih, const float* __restrict__ bih, const float* __restrict__ bhh,
    float* __restrict__ gx0, float* __restrict__ gx1) {
    __shared__ __align__(16) _Float16 Xh[128 * 72];
    __shared__ __align__(16) _Float16 Wh[128 * 72];
    int b = blockIdx.x, gy = blockIdx.y, tid = threadIdx.x;

    if (gy == 5) {  // fused k_encgx1: dir1 gates at t=127
        float* shf = (float*)Xh;     // 192 floats scratch
        if (tid < 192) {
            const float* src = (tid < 64 ? hs0 : (tid < 128 ? hs1 : hs2));
            shf[tid] = src[b * 8192 + 127 * 64 + (tid & 63)];
        }
        __syncthreads();
        const float* w1 = wih + 600 * 192;
        for (int g = tid; g < 600; g += 256) {
            float acc = bih[600 + g] + bhh[600 + g];
            const float4* wr = (const float4*)(w1 + g * 192);
            #pragma unroll 8
            for (int q = 0; q < 48; ++q) {
                float4 wv = wr[q];
                float4 hv = *(const float4*)&shf[q * 4];
                acc = fmaf(wv.x, hv.x, acc);
                acc = fmaf(wv.y, hv.y, acc);
                acc = fmaf(wv.z, hv.z, acc);
                acc = fmaf(wv.w, hv.w, acc);
            }
            gx1[b * 600 + g] = acc;
        }
        return;
    }

    int g0 = gy * 128;
    int ty = tid >> 4, tx = tid & 15;     // 16 t-groups x 16 g-groups, 8x8 each
    float acc[8][8];
    #pragma unroll
    for (int i = 0; i < 8; ++i)
        #pragma unroll
        for (int j = 0; j < 8; ++j) acc[i][j] = 0.f;
    const float* hsb[3] = {hs0 + b * 8192, hs1 + b * 8192, hs2 + b * 8192};

    for (int c = 0; c < 3; ++c) {
        const float4* src = (const float4*)hsb[c];
        for (int f = tid; f < 2048; f += 256) {
            int t = f >> 4, k4 = f & 15;
            float4 v = src[f];
            int pos = (((k4 >> 1) ^ ((t >> 3) & 7)) << 1) + (k4 & 1);
            *(uint2*)&Xh[t * 72 + pos * 4] = make_uint2(pku(v.x, v.y), pku(v.z, v.w));
        }
        for (int f = tid; f < 2048; f += 256) {
            int g = f >> 4, k4 = f & 15;
            int gg = g0 + g;
            float4 v = (gg < 600) ? *(const float4*)&wih[gg * 192 + c * 64 + k4 * 4]
                                  : make_float4(0.f, 0.f, 0.f, 0.f);
            int pos = (((k4 >> 1) ^ ((g >> 3) & 7)) << 1) + (k4 & 1);
            *(uint2*)&Wh[g * 72 + pos * 4] = make_uint2(pku(v.x, v.y), pku(v.z, v.w));
        }
        __syncthreads();
        #pragma unroll
        for (int k8 = 0; k8 < 8; ++k8) {
            uint4 av[8];
            #pragma unroll
            for (int i = 0; i < 8; ++i) {
                int row = ty * 8 + i;
                av[i] = *(const uint4*)&Xh[row * 72 + (k8 ^ ((row >> 3) & 7)) * 8];
            }
            #pragma unroll
            for (int j = 0; j < 8; ++j) {
                int row = tx * 8 + j;
                uint4 bv = *(const uint4*)&Wh[row * 72 + (k8 ^ ((row >> 3) & 7)) * 8];
                v2h b0 = upk(bv.x), b1 = upk(bv.y), b2 = upk(bv.z), b3 = upk(bv.w);
                #pragma unroll
                for (int i = 0; i < 8; ++i) {
                    acc[i][j] = fdot2(upk(av[i].x), b0, acc[i][j]);
                    acc[i][j] = fdot2(upk(av[i].y), b1, acc[i][j]);
                    acc[i][j] = fdot2(upk(av[i].z), b2, acc[i][j]);
                    acc[i][j] = fdot2(upk(av[i].w), b3, acc[i][j]);
                }
            }
        }
        __syncthreads();
    }
    // epilogue: + bias, store fp32
    #pragma unroll
    for (int i = 0; i < 8; ++i) {
        int t = ty * 8 + i;
        float* orow = gx0 + (b * 128 + t) * 600;
        #pragma unroll
        for (int jj = 0; jj < 2; ++jj) {
            int gbase = g0 + tx * 8 + jj * 4;
            if (gbase + 3 < 600) {
                float4 o;
                o.x = acc[i][jj * 4 + 0] + bih[gbase + 0] + bhh[gbase + 0];
                o.y = acc[i][jj * 4 + 1] + bih[gbase + 1] + bhh[gbase + 1];
                o.z = acc[i][jj * 4 + 2] + bih[gbase + 2] + bhh[gbase + 2];
                o.w = acc[i][jj * 4 + 3] + bih[gbase + 3] + bhh[gbase + 3];
                *(float4*)&orow[gbase] = o;
            } else {
                for (int e = 0; e < 4; ++e) {
                    int g = gbase + e;
                    if (g < 600) orow[g] = acc[i][jj * 4 + e] + bih[g] + bhh[g];
                }
            }
        }
    }
}

// ---------------- prefix sums of dec_wih rows: PT[k][dg], k=0..300 ----------------
__global__ void k_ptpref(const float* __restrict__ dwih, float* __restrict__ PT) {
    int dg = blockIdx.x * 256 + threadIdx.x;
    if (dg >= 1200) return;
    const float* wr = dwih + dg * 300;
    float run = 0.f;
    PT[dg] = 0.f;
    for (int k = 0; k < 300; ++k) {
        run += wr[k];
        PT[(k + 1) * 1200 + dg] = run;
    }
}

// ---------------- PD[(dirt*600+g)*4 + seg] ----------------
__global__ void k_pd(const float* __restrict__ PT, float* __restrict__ PD) {
    int id = blockIdx.x * 256 + threadIdx.x;
    if (id >= 153600) return;                 // 2*128*600
    int g = id % 600;
    int tt = id / 600;
    int t = tt & 127, dir = tt >> 7;
    int dg = dir * 600 + g;
    int base = t * 300;
    int j0 = base >> 7;
    int ke1 = (j0 + 1) * 128 - base;
    int ke2 = ke1 + 128; ke2 = ke2 > 300 ? 300 : ke2;
    int ke3 = ke1 + 256; ke3 = ke3 > 300 ? 300 : ke3;
    float p1 = PT[ke1 * 1200 + dg];
    float p2 = PT[ke2 * 1200 + dg];
    float p3 = PT[ke3 * 1200 + dg];
    float p4 = PT[300 * 1200 + dg];
    float4 o = {p1, p2 - p1, p3 - p2, p4 - p3};
    *(float4*)&PD[id * 4] = o;
}

// ---------------- encoder LSTM (R4 layout): thread = gate row; lane quad = hidden unit ----------------
__global__ __launch_bounds__(640, 3) void k_enclstm(
    const float* __restrict__ gx0, const float* __restrict__ gx1,
    const float* __restrict__ whh, float* __restrict__ h_end) {
    int bid = blockIdx.x, t = threadIdx.x;
    if (bid >= 128) {  // one bwd step from zero state on x_{127}
        int b = bid - 128;
        if (t < 150) {
            float ai = gx1[b * 600 + t];
            float ag = gx1[b * 600 + 300 + t];
            float ao = gx1[b * 600 + 450 + t];
            float c = sigm(ai) * tanhfast(ag);
            h_end[b * 300 + 150 + t] = sigm(ao) * tanhfast(c);
        }
        return;
    }
    __shared__ __align__(16) _Float16 hbuf[2][152];
    int b = bid;
    bool on = t < 600;
    int j = t >> 2, g4 = t & 3;
    int grow = g4 * 150 + j;          // raw gate row (i,f,g,o blocks of 150)
    v2h wv[76];
    #pragma unroll
    for (int p = 0; p < 76; ++p) wv[p] = pk2(0.f, 0.f);
    if (on) {
        const float* r = whh + grow * 150;
        #pragma unroll
        for (int p = 0; p < 75; ++p) wv[p] = pk2(r[2 * p], r[2 * p + 1]);
    }
    for (int i = t; i < 304; i += 640) ((_Float16*)hbuf)[i] = (_Float16)0.f;
    float c = 0.f;
    float xc = on ? gx0[(b * 128) * 600 + grow] : 0.f;
    barrier_lds();
    for (int s = 0; s < 128; ++s) {
        float xn = (on && s < 127) ? gx0[(b * 128 + s + 1) * 600 + grow] : 0.f;
        float s0 = 0.f, s1 = 0.f, s2 = 0.f, s3 = 0.f;
        const float4* hp = (const float4*)hbuf[s & 1];
        #pragma unroll
        for (int cc = 0; cc < 19; ++cc) {
            float4 hv = hp[cc];
            s0 = fdot2(wv[4 * cc + 0], __builtin_bit_cast(v2h, hv.x), s0);
            s1 = fdot2(wv[4 * cc + 1], __builtin_bit_cast(v2h, hv.y), s1);
            s2 = fdot2(wv[4 * cc + 2], __builtin_bit_cast(v2h, hv.z), s2);
            s3 = fdot2(wv[4 * cc + 3], __builtin_bit_cast(v2h, hv.w), s3);
        }
        float a = xc + ((s0 + s1) + (s2 + s3));
        bool isg = (g4 == 2);
        float sg = sigm(isg ? 2.f * a : a);
        float act = isg ? fmaf(2.f, sg, -1.f) : sg;   // tanh(x)=2*sigm(2x)-1
        float vf = __shfl_xor(act, 1);
        float vg = __shfl_xor(act, 2);
        float vo = __shfl_xor(vf, 2);
        if (on && g4 == 0) {
            c = fmaf(vf, c, act * vg);                // c = sigm(f)*c + sigm(i)*tanh(g)
            float h = vo * tanhfast(c);               // h = sigm(o)*tanh(c)
            hbuf[(s + 1) & 1][j] = (_Float16)h;
            if (s == 127) h_end[b * 300 + j] = h;
        }
        xc = xn;
        barrier_lds();
    }
}

// ---------------- decoder LSTM (R4 layout, both dirs), x-part via PD; fp16 dec out ----------------
__global__ __launch_bounds__(640, 3) void k_declstm(
    const float* __restrict__ PD, const float* __restrict__ hend,
    const float* __restrict__ whh_all, const float* __restrict__ bih,
    const float* __restrict__ bhh, _Float16* __restrict__ dec_out) {
    __shared__ __align__(16) float she[304];
    __shared__ __align__(16) _Float16 hbuf[2][152];
    int dir = blockIdx.x >> 7, b = blockIdx.x & 127;
    int t = threadIdx.x;
    bool on = t < 600;
    int j = t >> 2, g4 = t & 3;
    int grow = g4 * 150 + j;
    v2h wv[76];
    #pragma unroll
    for (int p = 0; p < 76; ++p) wv[p] = pk2(0.f, 0.f);
    float bias = 0.f;
    if (on) {
        const float* r = whh_all + dir * 90000 + grow * 150;
        #pragma unroll
        for (int p = 0; p < 75; ++p) wv[p] = pk2(r[2 * p], r[2 * p + 1]);
        bias = bih[dir * 600 + grow] + bhh[dir * 600 + grow];
    }
    for (int i = t; i < 304; i += 640) she[i] = (i < 300) ? hend[b * 300 + i] : 0.f;
    for (int i = t; i < 304; i += 640) ((_Float16*)hbuf)[i] = (_Float16)0.f;
    float c = 0.f;
    int t0 = dir ? 127 : 0;
    float4 pd = {0.f, 0.f, 0.f, 0.f};
    if (on) pd = *(const float4*)&PD[((dir * 128 + t0) * 600 + grow) * 4];
    barrier_lds();
    for (int s = 0; s < 128; ++s) {
        int tt = dir ? (127 - s) : s;
        float4 pdn = {0.f, 0.f, 0.f, 0.f};
        if (on && s < 127) {
            int tn = dir ? (126 - s) : (s + 1);
            pdn = *(const float4*)&PD[((dir * 128 + tn) * 600 + grow) * 4];
        }
        int j0 = (tt * 300) >> 7;
        float e0 = she[j0], e1 = she[j0 + 1], e2 = she[j0 + 2], e3 = she[j0 + 3];
        float a = bias + e0 * pd.x + e1 * pd.y + e2 * pd.z + e3 * pd.w;
        float s0 = 0.f, s1 = 0.f, s2 = 0.f, s3 = 0.f;
        const float4* hp = (const float4*)hbuf[s & 1];
        #pragma unroll
        for (int cc = 0; cc < 19; ++cc) {
            float4 hv = hp[cc];
            s0 = fdot2(wv[4 * cc + 0], __builtin_bit_cast(v2h, hv.x), s0);
            s1 = fdot2(wv[4 * cc + 1], __builtin_bit_cast(v2h, hv.y), s1);
            s2 = fdot2(wv[4 * cc + 2], __builtin_bit_cast(v2h, hv.z), s2);
            s3 = fdot2(wv[4 * cc + 3], __builtin_bit_cast(v2h, hv.w), s3);
        }
        a += (s0 + s1) + (s2 + s3);
        bool isg = (g4 == 2);
        float sg = sigm(isg ? 2.f * a : a);
        float act = isg ? fmaf(2.f, sg, -1.f) : sg;
        float vf = __shfl_xor(act, 1);
        float vg = __shfl_xor(act, 2);
        float vo = __shfl_xor(vf, 2);
        if (on && g4 == 0) {
            c = fmaf(vf, c, act * vg);
            float h = vo * tanhfast(c);
            hbuf[(s + 1) & 1][j] = (_Float16)h;
            dec_out[(b * 128 + tt) * 300 + dir * 150 + j] = (_Float16)h;
        }
        pd = pdn;
        barrier_lds();
    }
}

// ---------------- final: out = dec(fp16) @ fc_w^T + fc_b, fp16 dot2 ----------------
__global__ __launch_bounds__(256) void k_fingemm(const _Float16* __restrict__ decH,
                                                 const float* __restrict__ fw,
                                                 const float* __restrict__ fb,
                                                 float* __restrict__ out) {
    __shared__ __align__(16) unsigned AsT[16 * 68];  // [kk2][m] v2h
    __shared__ __align__(16) unsigned FwT[16 * 68];  // [kk2][n] v2h
    int r0 = blockIdx.x * 64, tid = threadIdx.x;
    int ty = tid >> 4, tx = tid & 15;
    float acc[4][4];
    #pragma unroll
    for (int r = 0; r < 4; ++r)
        #pragma unroll
        for (int c = 0; c < 4; ++c) acc[r][c] = 0.f;
    for (int kc = 0; kc < 10; ++kc) {
        int k0 = kc * 32;
        for (int f = tid; f < 1024; f += 256) {
            int m = f >> 4, kk2 = f & 15;
            int k = k0 + kk2 * 2;
            AsT[kk2 * 68 + m] =
                (k + 1 < 300) ? *(const unsigned*)&decH[(r0 + m) * 300 + k] : 0u;
        }
        for (int f = tid; f < 1024; f += 256) {
            int n = f >> 4, kk2 = f & 15;
            int k = k0 + kk2 * 2;
            FwT[kk2 * 68 + n] =
                (k + 1 < 300) ? pku(fw[n * 300 + k], fw[n * 300 + k + 1]) : 0u;
        }
        __syncthreads();
        #pragma unroll 4
        for (int kk2 = 0; kk2 < 16; ++kk2) {
            uint4 a4 = *(const uint4*)&AsT[kk2 * 68 + ty * 4];
            uint4 w4 = *(const uint4*)&FwT[kk2 * 68 + tx * 4];
            v2h a0 = upk(a4.x), a1 = upk(a4.y), a2 = upk(a4.z), a3 = upk(a4.w);
            v2h w0 = upk(w4.x), w1 = upk(w4.y), w2 = upk(w4.z), w3 = upk(w4.w);
            acc[0][0] = fdot2(a0, w0, acc[0][0]); acc[0][1] = fdot2(a0, w1, acc[0][1]);
            acc[0][2] = fdot2(a0, w2, acc[0][2]); acc[0][3] = fdot2(a0, w3, acc[0][3]);
            acc[1][0] = fdot2(a1, w0, acc[1][0]); acc[1][1] = fdot2(a1, w1, acc[1][1]);
            acc[1][2] = fdot2(a1, w2, acc[1][2]); acc[1][3] = fdot2(a1, w3, acc[1][3]);
            acc[2][0] = fdot2(a2, w0, acc[2][0]); acc[2][1] = fdot2(a2, w1, acc[2][1]);
            acc[2][2] = fdot2(a2, w2, acc[2][2]); acc[2][3] = fdot2(a2, w3, acc[2][3]);
            acc[3][0] = fdot2(a3, w0, acc[3][0]); acc[3][1] = fdot2(a3, w1, acc[3][1]);
            acc[3][2] = fdot2(a3, w2, acc[3][2]); acc[3][3] = fdot2(a3, w3, acc[3][3]);
        }
        __syncthreads();
    }
    for (int r = 0; r < 4; ++r) {
        int m = r0 + ty * 4 + r;
        float4 o4;
        o4.x = acc[r][0] + fb[tx * 4 + 0];
        o4.y = acc[r][1] + fb[tx * 4 + 1];
        o4.z = acc[r][2] + fb[tx * 4 + 2];
        o4.w = acc[r][3] + fb[tx * 4 + 3];
        *(float4*)&out[m * 64 + tx * 4] = o4;
    }
}

// ---------------- host launcher ----------------
extern "C" void kernel_launch(void* const* d_in, const int* in_sizes, int n_in,
                              void* d_out, int out_size, void* d_ws, size_t ws_size,
                              hipStream_t stream) {
    const float* x = (const float*)d_in[0];
    const float* c2w = (const float*)d_in[3];
    const float* c2b = (const float*)d_in[4];
    const float* c3w = (const float*)d_in[5];
    const float* c3b = (const float*)d_in[6];
    const float* gatw = (const float*)d_in[7];
    const float* gatas = (const float*)d_in[8];
    const float* gatad = (const float*)d_in[9];
    const float* gatb = (const float*)d_in[10];
    const float* gcnw = (const float*)d_in[11];
    const float* gcnb = (const float*)d_in[12];
    const float* lwih = (const float*)d_in[13];
    const float* lwhh = (const float*)d_in[14];
    const float* lbih = (const float*)d_in[15];
    const float* lbhh = (const float*)d_in[16];
    const float* dwih = (const float*)d_in[17];
    const float* dwhh = (const float*)d_in[18];
    const float* dbih = (const float*)d_in[19];
    const float* dbhh = (const float*)d_in[20];
    const float* fcw = (const float*)d_in[21];
    const float* fcb = (const float*)d_in[22];
    float* out = (float*)d_out;
    float* ws = (float*)d_ws;

    float* hs0 = ws;                    // 1,048,576
    float* hs1 = ws + 1048576;          // 1,048,576
    float* hs2 = ws + 2097152;          // 1,048,576
    float* gx0 = ws + 3145728;          // 9,830,400
    float* gx1 = ws + 12976128;         // 76,800
    float* hend = ws + 13052928;        // 38,400
    float* PT = ws + 13091328;          // 361,200
    _Float16* decH = (_Float16*)(ws + 13452528);  // 4,915,200 halfs
    float* PD = hs0;                    // overlays hs0 (dead after encgemm2)

    k_conv2<<<dim3(128, 2, 2), 256, (70 * 68 + 7 * 16 * 256) * 4, stream>>>(
        x, c2w, c2b, c3w, c3b, hs1, hs2);
    for (int l = 0; l < 2; ++l)
        k_stgat<<<dim3(128, 3), 256, 77824, stream>>>(x, hs0, hs1, hs2, gatw, gatas,
                                                      gatad, gatb, gcnw, gcnb, l);
    k_encgemm2<<<dim3(128, 6), 256, 0, stream>>>(hs0, hs1, hs2, lwih, lbih, lbhh, gx0, gx1);
    k_ptpref<<<5, 256, 0, stream>>>(dwih, PT);
    k_pd<<<600, 256, 0, stream>>>(PT, PD);   // after encgemm2: hs0 region now dead
    k_enclstm<<<256, 640, 0, stream>>>(gx0, gx1, lwhh, hend);
    k_declstm<<<256, 640, 0, stream>>>(PD, hend, dwhh, dbih, dbhh, decH);
    k_fingemm<<<256, 256, 0, stream>>>(decH, fcw, fcb, out);
}